// Round 1
// baseline (1251.630 us; speedup 1.0000x reference)
//
#include <hip/hip_runtime.h>

// ---------------- workspace layout (float offsets) ----------------
constexpr int B_SZ = 1024;
constexpr int L0 = 2048;
constexpr size_t OFF_POOLED = 0;                 // 1024*8
constexpr size_t OFF_TOPKI  = 8192;              // 2048 ints
constexpr size_t OFF_TOPKG  = 10240;             // 2048 floats
constexpr size_t OFF_KAB    = 12288;             // 896 floats
constexpr size_t OFF_COMB   = 16384;             // 1024*16384
constexpr size_t OFF_P      = 16384 + 16777216;  // 16*1024*64

// ---------------- pooling kernel: pooled[b,c] = mean_l relu(conv1(x)) ----------------
__global__ __launch_bounds__(256) void pool_kernel(const float* __restrict__ x,
    const float* __restrict__ c1w, const float* __restrict__ c1b, float* __restrict__ pooled)
{
    __shared__ float xbuf[2050];
    __shared__ float red[8 * 256];
    int b = blockIdx.x, tid = threadIdx.x;
    const float* xr = x + (size_t)b * L0;
    for (int i = tid; i < 2050; i += 256) xbuf[i] = (i >= 1 && i <= L0) ? xr[i - 1] : 0.f;
    __syncthreads();
    float w[24], bb[8];
#pragma unroll
    for (int i = 0; i < 24; i++) w[i] = c1w[i];
#pragma unroll
    for (int c = 0; c < 8; c++) bb[c] = c1b[c];
    float acc[8];
#pragma unroll
    for (int c = 0; c < 8; c++) acc[c] = 0.f;
    for (int l = tid; l < L0; l += 256) {
        float xm = xbuf[l], x0 = xbuf[l + 1], xp = xbuf[l + 2];
#pragma unroll
        for (int c = 0; c < 8; c++)
            acc[c] += fmaxf(fmaf(w[3 * c], xm, fmaf(w[3 * c + 1], x0, fmaf(w[3 * c + 2], xp, bb[c]))), 0.f);
    }
#pragma unroll
    for (int c = 0; c < 8; c++) red[c * 256 + tid] = acc[c];
    __syncthreads();
    for (int off = 128; off > 0; off >>= 1) {
        if (tid < off) {
#pragma unroll
            for (int c = 0; c < 8; c++) red[c * 256 + tid] += red[c * 256 + tid + off];
        }
        __syncthreads();
    }
    if (tid < 8) pooled[b * 8 + tid] = red[tid * 256] * (1.f / L0);
}

// ---------------- BN-fold precompute: kA = g/sqrt(v+eps), kB = (conv_b - m)*kA + bn_b ----------------
__global__ void bn_prep(
    const float* __restrict__ eb1, const float* __restrict__ g1, const float* __restrict__ bb1,
    const float* __restrict__ m1, const float* __restrict__ v1,
    const float* __restrict__ eb2, const float* __restrict__ g2, const float* __restrict__ bb2,
    const float* __restrict__ m2, const float* __restrict__ v2,
    const float* __restrict__ eb3, const float* __restrict__ g3, const float* __restrict__ bb3,
    const float* __restrict__ m3, const float* __restrict__ v3,
    float* __restrict__ kAB)
{
    int i = blockIdx.x * 256 + threadIdx.x;
    if (i < 64) {
        float A = g1[i] / sqrtf(v1[i] + 1e-5f);
        kAB[i] = A; kAB[64 + i] = fmaf(eb1[i] - m1[i], A, bb1[i]);
    } else if (i < 192) {
        int k = i - 64;
        float A = g2[k] / sqrtf(v2[k] + 1e-5f);
        kAB[128 + k] = A; kAB[256 + k] = fmaf(eb2[k] - m2[k], A, bb2[k]);
    } else if (i < 448) {
        int k = i - 192;
        float A = g3[k] / sqrtf(v3[k] + 1e-5f);
        kAB[384 + k] = A; kAB[640 + k] = fmaf(eb3[k] - m3[k], A, bb3[k]);
    }
}

// ---------------- router: softmax, top-2, gates, aux loss ----------------
__global__ __launch_bounds__(1024) void router_kernel(const float* __restrict__ pooled,
    const float* __restrict__ rw, const float* __restrict__ rb,
    int* __restrict__ tidx, float* __restrict__ tg, float* __restrict__ aux)
{
    __shared__ float pr[4][1024];
    int b = threadIdx.x;
    float p[8];
#pragma unroll
    for (int c = 0; c < 8; c++) p[c] = pooled[b * 8 + c];
    float lg[4];
#pragma unroll
    for (int e = 0; e < 4; e++) {
        float a = rb[e];
#pragma unroll
        for (int c = 0; c < 8; c++) a = fmaf(p[c], rw[e * 8 + c], a);
        lg[e] = a;
    }
    float m = fmaxf(fmaxf(lg[0], lg[1]), fmaxf(lg[2], lg[3]));
    float pe[4]; float s = 0.f;
#pragma unroll
    for (int e = 0; e < 4; e++) { pe[e] = expf(lg[e] - m); s += pe[e]; }
    float inv = 1.f / s;
#pragma unroll
    for (int e = 0; e < 4; e++) pe[e] *= inv;
    int e0 = 0;
#pragma unroll
    for (int e = 1; e < 4; e++) if (pe[e] > pe[e0]) e0 = e;
    int e1 = -1;
#pragma unroll
    for (int e = 0; e < 4; e++) if (e != e0 && (e1 < 0 || pe[e] > pe[e1])) e1 = e;
    float s2 = pe[e0] + pe[e1];
    tidx[b * 2] = e0; tidx[b * 2 + 1] = e1;
    tg[b * 2] = pe[e0] / s2; tg[b * 2 + 1] = pe[e1] / s2;
#pragma unroll
    for (int e = 0; e < 4; e++) pr[e][b] = pe[e];
    __syncthreads();
    for (int off = 512; off > 0; off >>= 1) {
        if (b < off) {
#pragma unroll
            for (int e = 0; e < 4; e++) pr[e][b] += pr[e][b + off];
        }
        __syncthreads();
    }
    if (b == 0) {
        float mp[4]; float mm = 0.f;
#pragma unroll
        for (int e = 0; e < 4; e++) { mp[e] = pr[e][0] * (1.f / 1024.f); mm += mp[e]; }
        mm *= 0.25f;
        float var = 0.f;
#pragma unroll
        for (int e = 0; e < 4; e++) { float d = mp[e] - mm; var += d * d; }
        var *= (1.f / 3.f);
        float cv = sqrtf(var) / (mm + 1e-10f);
        aux[0] = cv * cv;
    }
}

// ---------------- fused expert chain: conv-bn-relu-pool x3, tiled, per (b, slot) ----------------
// generic stage: conv(k=3,'same') + BN + ReLU + maxpool2
// in LDS buffer: [CI][SIN], logical start a_in = 2*a_out-1; out LDS: [CO][SOUT]
template<int CO, int CI, int JOUT, int SIN, int SOUT, int LOUT>
__device__ __forceinline__ void stage_conv(
    const float* __restrict__ w,   // [CO][CI][3] (expert-offset applied)
    const float* __restrict__ kA, const float* __restrict__ kB,
    const float* __restrict__ in, float* __restrict__ out,
    int a_out, int tid)
{
    constexpr int TPC = 256 / CO;            // threads per output channel
    constexpr int NJ = (JOUT + TPC - 1) / TPC;
    const int co = tid / TPC;
    const int jb = tid % TPC;
    const float A = kA[co], Bb = kB[co];
    float wreg[CI * 3];
#pragma unroll
    for (int i = 0; i < CI * 3; i++) wreg[i] = w[co * CI * 3 + i];
    for (int jj = 0; jj < NJ; jj++) {
        int j = jb + jj * TPC;
        if constexpr (JOUT % TPC != 0) { if (j >= JOUT) break; }
        int l = a_out + j;
        float val = 0.f;
        if (l >= 0 && l < LOUT) {
            float acc0 = 0.f, acc1 = 0.f;
#pragma unroll
            for (int ci = 0; ci < CI; ++ci) {
                const float* ip = in + ci * SIN + 2 * j;
                float2 p0 = *reinterpret_cast<const float2*>(ip);
                float2 p1 = *reinterpret_cast<const float2*>(ip + 2);
                float w0 = wreg[3 * ci], w1 = wreg[3 * ci + 1], w2 = wreg[3 * ci + 2];
                acc0 = fmaf(w2, p1.x, fmaf(w1, p0.y, fmaf(w0, p0.x, acc0)));
                acc1 = fmaf(w2, p1.y, fmaf(w1, p1.x, fmaf(w0, p0.y, acc1)));
            }
            val = fmaxf(fmaxf(fmaf(acc0, A, Bb), fmaf(acc1, A, Bb)), 0.f);
        }
        out[co * SOUT + j] = val;
    }
}

__global__ __launch_bounds__(256) void expert_kernel(
    const float* __restrict__ x, const float* __restrict__ c1w, const float* __restrict__ c1b,
    const float* __restrict__ ew1, const float* __restrict__ ew2, const float* __restrict__ ew3,
    const float* __restrict__ kAB, const int* __restrict__ tidx, const float* __restrict__ tg,
    float* __restrict__ combined)
{
    __shared__ __align__(16) float xbuf[2050];
    __shared__ __align__(16) float bufA[4224];   // stage0 out 8x528 / stage2 out 32x132
    __shared__ __align__(16) float bufB[4224];   // stage1 out 16x264 / stage3 out 64x66
    const int b = blockIdx.x, tid = threadIdx.x;
    const float* xr = x + (size_t)b * L0;
    for (int i = tid; i < 2050; i += 256) xbuf[i] = (i >= 1 && i <= L0) ? xr[i - 1] : 0.f;
    float* cb = combined + (size_t)b * 16384;

    for (int slot = 0; slot < 2; ++slot) {
        const int e = tidx[b * 2 + slot];
        const float g = tg[b * 2 + slot];
        const float* w1 = ew1 + e * 16 * 8 * 3;
        const float* w2 = ew2 + e * 32 * 16 * 3;
        const float* w3 = ew3 + e * 64 * 32 * 3;
        const float* kA1 = kAB + e * 16;        const float* kB1 = kAB + 64 + e * 16;
        const float* kA2 = kAB + 128 + e * 32;  const float* kB2 = kAB + 256 + e * 32;
        const float* kA3 = kAB + 384 + e * 64;  const float* kB3 = kAB + 640 + e * 64;
        for (int t = 0; t < 4; ++t) {
            const int a3 = 64 * t;
            __syncthreads();
            // ---- stage0: conv1+ReLU tile -> bufA [8][528], a0 = 8*a3-7, J=526 ----
            {
                int co = tid / 32, jb = tid % 32;
                float wa = c1w[co * 3], wb = c1w[co * 3 + 1], wc = c1w[co * 3 + 2], bb = c1b[co];
                int a0 = 8 * a3 - 7;
                for (int jj = 0; jj < 17; jj++) {
                    int j = jb + jj * 32;
                    if (j >= 526) break;
                    int l = a0 + j;
                    float v = 0.f;
                    if (l >= 0 && l < L0)
                        v = fmaxf(fmaf(wa, xbuf[l], fmaf(wb, xbuf[l + 1], fmaf(wc, xbuf[l + 2], bb))), 0.f);
                    bufA[co * 528 + j] = v;
                }
            }
            __syncthreads();
            stage_conv<16, 8, 262, 528, 264, 1024>(w1, kA1, kB1, bufA, bufB, 4 * a3 - 3, tid);
            __syncthreads();
            stage_conv<32, 16, 130, 264, 132, 512>(w2, kA2, kB2, bufB, bufA, 2 * a3 - 1, tid);
            __syncthreads();
            stage_conv<64, 32, 64, 132, 66, 256>(w3, kA3, kB3, bufA, bufB, a3, tid);
            __syncthreads();
            // ---- combine: gate-weighted write / accumulate ----
            for (int i = tid; i < 4096; i += 256) {
                int c = i >> 6, j = i & 63;
                float v = g * bufB[c * 66 + j];
                size_t o = (size_t)c * 256 + a3 + j;
                if (slot == 0) cb[o] = v; else cb[o] += v;
            }
        }
    }
}

// ---------------- fc1 split-K GEMM: P[kc][b][64] = partial(flat @ fc1_w.T) ----------------
__global__ __launch_bounds__(256) void fc1_kernel(const float* __restrict__ comb,
    const float* __restrict__ w, float* __restrict__ P)
{
    __shared__ __align__(16) float at[64 * 65];
    __shared__ __align__(16) float wt[64 * 65];
    int bc = blockIdx.x;   // 0..15 row chunk
    int kc = blockIdx.y;   // 0..15 k chunk
    int tid = threadIdx.x;
    int tx = tid & 15, ty = tid >> 4;
    float acc[4][4];
#pragma unroll
    for (int i = 0; i < 4; i++)
#pragma unroll
        for (int j = 0; j < 4; j++) acc[i][j] = 0.f;
    int b0 = bc * 64;
    for (int kt = 0; kt < 16; ++kt) {
        int k0 = kc * 1024 + kt * 64;
        __syncthreads();
        for (int i = tid; i < 4096; i += 256) {
            int r = i >> 6, kk = i & 63;
            at[r * 65 + kk] = comb[(size_t)(b0 + r) * 16384 + k0 + kk];
            wt[r * 65 + kk] = w[(size_t)r * 16384 + k0 + kk];
        }
        __syncthreads();
#pragma unroll 8
        for (int kk = 0; kk < 64; kk++) {
            float av[4], wv[4];
#pragma unroll
            for (int i = 0; i < 4; i++) av[i] = at[(ty * 4 + i) * 65 + kk];
#pragma unroll
            for (int j = 0; j < 4; j++) wv[j] = wt[(tx * 4 + j) * 65 + kk];
#pragma unroll
            for (int i = 0; i < 4; i++)
#pragma unroll
                for (int j = 0; j < 4; j++) acc[i][j] = fmaf(av[i], wv[j], acc[i][j]);
        }
    }
    float* Pp = P + (size_t)kc * 65536;
#pragma unroll
    for (int i = 0; i < 4; i++)
#pragma unroll
        for (int j = 0; j < 4; j++)
            Pp[(size_t)(b0 + ty * 4 + i) * 64 + tx * 4 + j] = acc[i][j];
}

// ---------------- reduce partials + bias + relu + fc2 ----------------
__global__ __launch_bounds__(256) void fc2_kernel(const float* __restrict__ P,
    const float* __restrict__ f1b, const float* __restrict__ w2, const float* __restrict__ b2,
    float* __restrict__ out)
{
    int b = blockIdx.x * 256 + threadIdx.x;  // 0..1023
    float z[64];
#pragma unroll
    for (int n = 0; n < 64; n++) z[n] = 0.f;
    for (int kc = 0; kc < 16; kc++) {
        const float* Pp = P + (size_t)kc * 65536 + (size_t)b * 64;
#pragma unroll
        for (int n = 0; n < 64; n++) z[n] += Pp[n];
    }
    float o[5] = {0.f, 0.f, 0.f, 0.f, 0.f};
#pragma unroll
    for (int n = 0; n < 64; n++) {
        float zz = fmaxf(z[n] + f1b[n], 0.f);
#pragma unroll
        for (int c = 0; c < 5; c++) o[c] = fmaf(zz, w2[c * 64 + n], o[c]);
    }
#pragma unroll
    for (int c = 0; c < 5; c++) out[b * 5 + c] = o[c] + b2[c];
}

extern "C" void kernel_launch(void* const* d_in, const int* in_sizes, int n_in,
                              void* d_out, int out_size, void* d_ws, size_t ws_size,
                              hipStream_t stream)
{
    const float* x   = (const float*)d_in[0];
    const float* c1w = (const float*)d_in[1];
    const float* c1b = (const float*)d_in[2];
    const float* ew1 = (const float*)d_in[3];
    const float* eb1 = (const float*)d_in[4];
    const float* g1  = (const float*)d_in[5];
    const float* bb1 = (const float*)d_in[6];
    const float* m1  = (const float*)d_in[7];
    const float* v1  = (const float*)d_in[8];
    const float* ew2 = (const float*)d_in[9];
    const float* eb2 = (const float*)d_in[10];
    const float* g2  = (const float*)d_in[11];
    const float* bb2 = (const float*)d_in[12];
    const float* m2  = (const float*)d_in[13];
    const float* v2  = (const float*)d_in[14];
    const float* ew3 = (const float*)d_in[15];
    const float* eb3 = (const float*)d_in[16];
    const float* g3  = (const float*)d_in[17];
    const float* bb3 = (const float*)d_in[18];
    const float* m3  = (const float*)d_in[19];
    const float* v3  = (const float*)d_in[20];
    const float* rw  = (const float*)d_in[21];
    const float* rb  = (const float*)d_in[22];
    const float* f1w = (const float*)d_in[23];
    const float* f1b = (const float*)d_in[24];
    const float* f2w = (const float*)d_in[25];
    const float* f2b = (const float*)d_in[26];

    float* ws     = (float*)d_ws;
    float* pooled = ws + OFF_POOLED;
    int*   tidx   = (int*)(ws + OFF_TOPKI);
    float* tg     = ws + OFF_TOPKG;
    float* kAB    = ws + OFF_KAB;
    float* comb   = ws + OFF_COMB;
    float* P      = ws + OFF_P;
    float* out    = (float*)d_out;

    hipLaunchKernelGGL(pool_kernel, dim3(1024), dim3(256), 0, stream, x, c1w, c1b, pooled);
    hipLaunchKernelGGL(bn_prep, dim3(2), dim3(256), 0, stream,
                       eb1, g1, bb1, m1, v1, eb2, g2, bb2, m2, v2, eb3, g3, bb3, m3, v3, kAB);
    hipLaunchKernelGGL(router_kernel, dim3(1), dim3(1024), 0, stream, pooled, rw, rb, tidx, tg, out + 5120);
    hipLaunchKernelGGL(expert_kernel, dim3(1024), dim3(256), 0, stream,
                       x, c1w, c1b, ew1, ew2, ew3, kAB, tidx, tg, comb);
    hipLaunchKernelGGL(fc1_kernel, dim3(16, 16), dim3(256), 0, stream, comb, f1w, P);
    hipLaunchKernelGGL(fc2_kernel, dim3(4), dim3(256), 0, stream, P, f1b, f2w, f2b, out);
}

// Round 2
// 725.263 us; speedup vs baseline: 1.7258x; 1.7258x over previous
//
#include <hip/hip_runtime.h>

// ---------------- workspace layout (float offsets) ----------------
constexpr int L0 = 2048;
constexpr size_t OFF_POOLED = 0;                  // 1024*8
constexpr size_t OFF_TOPKI  = 8192;               // 2048 ints
constexpr size_t OFF_TOPKG  = 10240;              // 2048 floats
constexpr size_t OFF_B1     = 12288;              // 64
constexpr size_t OFF_B2     = 12352;              // 128
constexpr size_t OFF_B3     = 12480;              // 256
constexpr size_t OFF_W1P    = 12800;              // 2048  [e][ci8][co16][4]
constexpr size_t OFF_W2P    = 14848;              // 8192  [e][ci16][co32][4]
constexpr size_t OFF_W3P    = 23040;              // 32768 [e][ci32][co64][4]
constexpr size_t OFF_COMB   = 57344;              // 1024*16384
constexpr size_t OFF_P      = 57344 + 16777216;   // 8*1024*64

// ---------------- pooling kernel: pooled[b,c] = mean_l relu(conv1(x)) ----------------
__global__ __launch_bounds__(256) void pool_kernel(const float* __restrict__ x,
    const float* __restrict__ c1w, const float* __restrict__ c1b, float* __restrict__ pooled)
{
    __shared__ float xbuf[2050];
    __shared__ float red[8 * 256];
    int b = blockIdx.x, tid = threadIdx.x;
    const float* xr = x + (size_t)b * L0;
    for (int i = tid; i < 2050; i += 256) xbuf[i] = (i >= 1 && i <= L0) ? xr[i - 1] : 0.f;
    __syncthreads();
    float w[24], bb[8];
#pragma unroll
    for (int i = 0; i < 24; i++) w[i] = c1w[i];
#pragma unroll
    for (int c = 0; c < 8; c++) bb[c] = c1b[c];
    float acc[8];
#pragma unroll
    for (int c = 0; c < 8; c++) acc[c] = 0.f;
    for (int l = tid; l < L0; l += 256) {
        float xm = xbuf[l], x0 = xbuf[l + 1], xp = xbuf[l + 2];
#pragma unroll
        for (int c = 0; c < 8; c++)
            acc[c] += fmaxf(fmaf(w[3 * c], xm, fmaf(w[3 * c + 1], x0, fmaf(w[3 * c + 2], xp, bb[c]))), 0.f);
    }
#pragma unroll
    for (int c = 0; c < 8; c++) red[c * 256 + tid] = acc[c];
    __syncthreads();
    for (int off = 128; off > 0; off >>= 1) {
        if (tid < off) {
#pragma unroll
            for (int c = 0; c < 8; c++) red[c * 256 + tid] += red[c * 256 + tid + off];
        }
        __syncthreads();
    }
    if (tid < 8) pooled[b * 8 + tid] = red[tid * 256] * (1.f / L0);
}

// ---------------- weight repack + BN fold ----------------
// w#p[e][ci][co][4] = ew#[e][co][ci][k] * A[e][co], pad k=3 with 0; b#p[e][co] = (eb-m)*A + bn_b
__global__ __launch_bounds__(256) void repack_kernel(
    const float* __restrict__ ew1, const float* __restrict__ eb1, const float* __restrict__ g1,
    const float* __restrict__ bb1, const float* __restrict__ m1, const float* __restrict__ v1,
    const float* __restrict__ ew2, const float* __restrict__ eb2, const float* __restrict__ g2,
    const float* __restrict__ bb2, const float* __restrict__ m2, const float* __restrict__ v2,
    const float* __restrict__ ew3, const float* __restrict__ eb3, const float* __restrict__ g3,
    const float* __restrict__ bb3, const float* __restrict__ m3, const float* __restrict__ v3,
    float* __restrict__ w1p, float* __restrict__ w2p, float* __restrict__ w3p,
    float* __restrict__ b1p, float* __restrict__ b2p, float* __restrict__ b3p)
{
    int i = blockIdx.x * 256 + threadIdx.x;
    if (i < 2048) {
        int k = i & 3, r = i >> 2;
        int co = r & 15, r2 = r >> 4;       // r2 = e*8+ci
        int ci = r2 & 7, e = r2 >> 3;
        int ec = e * 16 + co;
        float A = g1[ec] * rsqrtf(v1[ec] + 1e-5f);
        w1p[i] = (k < 3) ? ew1[(ec * 8 + ci) * 3 + k] * A : 0.f;
    } else if (i < 10240) {
        int ii = i - 2048;
        int k = ii & 3, r = ii >> 2;
        int co = r & 31, r2 = r >> 5;
        int ci = r2 & 15, e = r2 >> 4;
        int ec = e * 32 + co;
        float A = g2[ec] * rsqrtf(v2[ec] + 1e-5f);
        w2p[ii] = (k < 3) ? ew2[(ec * 16 + ci) * 3 + k] * A : 0.f;
    } else if (i < 43008) {
        int ii = i - 10240;
        int k = ii & 3, r = ii >> 2;
        int co = r & 63, r2 = r >> 6;
        int ci = r2 & 31, e = r2 >> 5;
        int ec = e * 64 + co;
        float A = g3[ec] * rsqrtf(v3[ec] + 1e-5f);
        w3p[ii] = (k < 3) ? ew3[(ec * 32 + ci) * 3 + k] * A : 0.f;
    } else if (i < 43456) {
        int j = i - 43008;
        if (j < 64)       { float A = g1[j] * rsqrtf(v1[j] + 1e-5f); b1p[j] = fmaf(eb1[j] - m1[j], A, bb1[j]); }
        else if (j < 192) { int q = j - 64;  float A = g2[q] * rsqrtf(v2[q] + 1e-5f); b2p[q] = fmaf(eb2[q] - m2[q], A, bb2[q]); }
        else              { int q = j - 192; float A = g3[q] * rsqrtf(v3[q] + 1e-5f); b3p[q] = fmaf(eb3[q] - m3[q], A, bb3[q]); }
    }
}

// ---------------- router: softmax, top-2, gates, aux loss ----------------
__global__ __launch_bounds__(1024) void router_kernel(const float* __restrict__ pooled,
    const float* __restrict__ rw, const float* __restrict__ rb,
    int* __restrict__ tidx, float* __restrict__ tg, float* __restrict__ aux)
{
    __shared__ float pr[4][1024];
    int b = threadIdx.x;
    float p[8];
#pragma unroll
    for (int c = 0; c < 8; c++) p[c] = pooled[b * 8 + c];
    float lg[4];
#pragma unroll
    for (int e = 0; e < 4; e++) {
        float a = rb[e];
#pragma unroll
        for (int c = 0; c < 8; c++) a = fmaf(p[c], rw[e * 8 + c], a);
        lg[e] = a;
    }
    float m = fmaxf(fmaxf(lg[0], lg[1]), fmaxf(lg[2], lg[3]));
    float pe[4]; float s = 0.f;
#pragma unroll
    for (int e = 0; e < 4; e++) { pe[e] = expf(lg[e] - m); s += pe[e]; }
    float inv = 1.f / s;
#pragma unroll
    for (int e = 0; e < 4; e++) pe[e] *= inv;
    int e0 = 0;
#pragma unroll
    for (int e = 1; e < 4; e++) if (pe[e] > pe[e0]) e0 = e;
    int e1 = -1;
#pragma unroll
    for (int e = 0; e < 4; e++) if (e != e0 && (e1 < 0 || pe[e] > pe[e1])) e1 = e;
    float s2 = pe[e0] + pe[e1];
    tidx[b * 2] = e0; tidx[b * 2 + 1] = e1;
    tg[b * 2] = pe[e0] / s2; tg[b * 2 + 1] = pe[e1] / s2;
#pragma unroll
    for (int e = 0; e < 4; e++) pr[e][b] = pe[e];
    __syncthreads();
    for (int off = 512; off > 0; off >>= 1) {
        if (b < off) {
#pragma unroll
            for (int e = 0; e < 4; e++) pr[e][b] += pr[e][b + off];
        }
        __syncthreads();
    }
    if (b == 0) {
        float mp[4]; float mm = 0.f;
#pragma unroll
        for (int e = 0; e < 4; e++) { mp[e] = pr[e][0] * (1.f / 1024.f); mm += mp[e]; }
        mm *= 0.25f;
        float var = 0.f;
#pragma unroll
        for (int e = 0; e < 4; e++) { float d = mp[e] - mm; var += d * d; }
        var *= (1.f / 3.f);
        float cv = sqrtf(var) / (mm + 1e-10f);
        aux[0] = cv * cv;
    }
}

// ---------------- expert chain stages ----------------
// Each thread: 2 output channels x 4 consecutive positions; weights from global (repacked,
// BN-folded); inputs from LDS as float4/float2. conv k=3 'same' + bias + relu + maxpool2.
template<int CO, int CI, int JOUT, int LOUT, int SIN, int SOUT, int PG, int SWEEPS>
__device__ __forceinline__ void stage(
    const float* __restrict__ wp,   // [CI][CO][4] for this expert
    const float* __restrict__ bp,   // [CO]
    const float* __restrict__ in, float* __restrict__ out,
    int a_out, int tid)
{
    const int cg = tid / PG;
    const int pg = tid % PG;
    const int co0 = 2 * cg;
    const float b0 = bp[co0], b1 = bp[co0 + 1];
#pragma unroll
    for (int s = 0; s < SWEEPS; ++s) {
        const int j0 = s * PG * 4 + pg * 4;
        if constexpr (JOUT % (PG * 4) != 0) { if (j0 >= JOUT) continue; }
        float aE[2][4], aO[2][4];
#pragma unroll
        for (int p = 0; p < 4; p++) { aE[0][p] = b0; aO[0][p] = b0; aE[1][p] = b1; aO[1][p] = b1; }
#pragma unroll
        for (int cb = 0; cb < CI / 4; ++cb) {
            float4 w[4][2];
#pragma unroll
            for (int ci = 0; ci < 4; ci++) {
                const float* wb = wp + ((cb * 4 + ci) * CO + co0) * 4;
                w[ci][0] = *reinterpret_cast<const float4*>(wb);
                w[ci][1] = *reinterpret_cast<const float4*>(wb + 4);
            }
#pragma unroll
            for (int ci = 0; ci < 4; ci++) {
                const float* ip = in + (cb * 4 + ci) * SIN + 2 * j0;
                float4 f0 = *reinterpret_cast<const float4*>(ip);
                float4 f1 = *reinterpret_cast<const float4*>(ip + 4);
                float2 f2 = *reinterpret_cast<const float2*>(ip + 8);
                float r[10] = {f0.x, f0.y, f0.z, f0.w, f1.x, f1.y, f1.z, f1.w, f2.x, f2.y};
#pragma unroll
                for (int c = 0; c < 2; c++) {
                    float w0 = c ? w[ci][1].x : w[ci][0].x;
                    float w1 = c ? w[ci][1].y : w[ci][0].y;
                    float w2 = c ? w[ci][1].z : w[ci][0].z;
#pragma unroll
                    for (int p = 0; p < 4; p++) {
                        aE[c][p] = fmaf(w0, r[2*p],   fmaf(w1, r[2*p+1], fmaf(w2, r[2*p+2], aE[c][p])));
                        aO[c][p] = fmaf(w0, r[2*p+1], fmaf(w1, r[2*p+2], fmaf(w2, r[2*p+3], aO[c][p])));
                    }
                }
            }
        }
#pragma unroll
        for (int c = 0; c < 2; c++) {
            float v[4];
#pragma unroll
            for (int p = 0; p < 4; p++) {
                int l = a_out + j0 + p;
                float vv = fmaxf(fmaxf(aE[c][p], aO[c][p]), 0.f);
                v[p] = (l >= 0 && l < LOUT) ? vv : 0.f;
            }
            float* op = out + (co0 + c) * SOUT + j0;
            if constexpr (JOUT % (PG * 4) == 0) {
                *reinterpret_cast<float4*>(op) = make_float4(v[0], v[1], v[2], v[3]);
            } else {
                if (j0 + 4 <= JOUT) {
                    *reinterpret_cast<float4*>(op) = make_float4(v[0], v[1], v[2], v[3]);
                } else {
#pragma unroll
                    for (int p = 0; p < 4; p++) if (j0 + p < JOUT) op[p] = v[p];
                }
            }
        }
    }
}

// stage3: CO=64, CI=32, JOUT=64, SIN=132; accumulates gated result into oa registers.
__device__ __forceinline__ void stage3_acc(
    const float* __restrict__ wp, const float* __restrict__ bp,
    const float* __restrict__ in, float g, float oa[2][2][4], int tid)
{
    const int cg = tid >> 3;
    const int pg = tid & 7;
    const int co0 = 2 * cg;
    const float b0 = bp[co0], b1 = bp[co0 + 1];
#pragma unroll
    for (int s = 0; s < 2; ++s) {
        const int j0 = s * 32 + pg * 4;
        float aE[2][4], aO[2][4];
#pragma unroll
        for (int p = 0; p < 4; p++) { aE[0][p] = b0; aO[0][p] = b0; aE[1][p] = b1; aO[1][p] = b1; }
#pragma unroll
        for (int cb = 0; cb < 8; ++cb) {
            float4 w[4][2];
#pragma unroll
            for (int ci = 0; ci < 4; ci++) {
                const float* wb = wp + ((cb * 4 + ci) * 64 + co0) * 4;
                w[ci][0] = *reinterpret_cast<const float4*>(wb);
                w[ci][1] = *reinterpret_cast<const float4*>(wb + 4);
            }
#pragma unroll
            for (int ci = 0; ci < 4; ci++) {
                const float* ip = in + (cb * 4 + ci) * 132 + 2 * j0;
                float4 f0 = *reinterpret_cast<const float4*>(ip);
                float4 f1 = *reinterpret_cast<const float4*>(ip + 4);
                float2 f2 = *reinterpret_cast<const float2*>(ip + 8);
                float r[10] = {f0.x, f0.y, f0.z, f0.w, f1.x, f1.y, f1.z, f1.w, f2.x, f2.y};
#pragma unroll
                for (int c = 0; c < 2; c++) {
                    float w0 = c ? w[ci][1].x : w[ci][0].x;
                    float w1 = c ? w[ci][1].y : w[ci][0].y;
                    float w2 = c ? w[ci][1].z : w[ci][0].z;
#pragma unroll
                    for (int p = 0; p < 4; p++) {
                        aE[c][p] = fmaf(w0, r[2*p],   fmaf(w1, r[2*p+1], fmaf(w2, r[2*p+2], aE[c][p])));
                        aO[c][p] = fmaf(w0, r[2*p+1], fmaf(w1, r[2*p+2], fmaf(w2, r[2*p+3], aO[c][p])));
                    }
                }
            }
        }
#pragma unroll
        for (int c = 0; c < 2; c++)
#pragma unroll
            for (int p = 0; p < 4; p++)
                oa[s][c][p] = fmaf(g, fmaxf(fmaxf(aE[c][p], aO[c][p]), 0.f), oa[s][c][p]);
    }
}

__global__ __launch_bounds__(256) void expert_kernel(
    const float* __restrict__ x, const float* __restrict__ c1w, const float* __restrict__ c1b,
    const float* __restrict__ w1p, const float* __restrict__ w2p, const float* __restrict__ w3p,
    const float* __restrict__ b1p, const float* __restrict__ b2p, const float* __restrict__ b3p,
    const int* __restrict__ tidx, const float* __restrict__ tg,
    float* __restrict__ comb)
{
    __shared__ __align__(16) float xbuf[532];
    __shared__ __align__(16) float bufA[4240];   // stage0 out [8][528] (+pad for halo reads)
    __shared__ __align__(16) float bufB[4240];   // stage1 out [16][264] (+pad)
    __shared__ __align__(16) float bufC[4224];   // stage2 out [32][132]
    const int tid = threadIdx.x;
    const int bt = blockIdx.x;
    const int b = bt >> 2, t = bt & 3;
    const int a3 = t * 64, a2 = 2 * a3 - 1, a1 = 4 * a3 - 3, a0 = 8 * a3 - 7;
    const float* xr = x + (size_t)b * L0;
    for (int i = tid; i < 528; i += 256) {
        int l = a0 - 1 + i;
        xbuf[i] = (l >= 0 && l < L0) ? xr[l] : 0.f;
    }
    __syncthreads();
    // stage0: conv1 + relu -> bufA [8][528], j < 526, l = a0 + j
    {
        int co = tid >> 5, jb = tid & 31;
        float wa = c1w[co * 3], wb = c1w[co * 3 + 1], wc = c1w[co * 3 + 2], bb = c1b[co];
        for (int j = jb; j < 526; j += 32) {
            int l = a0 + j;
            float v = 0.f;
            if (l >= 0 && l < L0)
                v = fmaxf(fmaf(wa, xbuf[j], fmaf(wb, xbuf[j + 1], fmaf(wc, xbuf[j + 2], bb))), 0.f);
            bufA[co * 528 + j] = v;
        }
    }
    float oa[2][2][4];
#pragma unroll
    for (int s = 0; s < 2; s++)
#pragma unroll
        for (int c = 0; c < 2; c++)
#pragma unroll
            for (int p = 0; p < 4; p++) oa[s][c][p] = 0.f;
    const int ea = tidx[b * 2], eb = tidx[b * 2 + 1];
    const float ga = tg[b * 2], gb = tg[b * 2 + 1];
#pragma unroll 1
    for (int slot = 0; slot < 2; ++slot) {
        const int e = slot ? eb : ea;
        const float g = slot ? gb : ga;
        __syncthreads();  // bufA ready / prev slot's bufC reads done, bufB free
        stage<16, 8, 262, 1024, 528, 264, 32, 3>(w1p + e * 512, b1p + e * 16, bufA, bufB, a1, tid);
        __syncthreads();
        stage<32, 16, 130, 512, 264, 132, 16, 3>(w2p + e * 2048, b2p + e * 32, bufB, bufC, a2, tid);
        __syncthreads();
        stage3_acc(w3p + e * 8192, b3p + e * 64, bufC, g, oa, tid);
    }
    // write gated combined output: comb[b][co][a3 + j]
    float* cp0 = comb + (size_t)b * 16384 + a3;
    const int co0 = (tid >> 3) * 2;
    const int jb0 = (tid & 7) * 4;
#pragma unroll
    for (int s = 0; s < 2; s++)
#pragma unroll
        for (int c = 0; c < 2; c++)
            *reinterpret_cast<float4*>(cp0 + (co0 + c) * 256 + s * 32 + jb0) =
                make_float4(oa[s][c][0], oa[s][c][1], oa[s][c][2], oa[s][c][3]);
}

// ---------------- fc1 split-K GEMM: P[kc][b][64] = partial(flat @ fc1_w.T) ----------------
__global__ __launch_bounds__(256) void fc1_kernel(const float* __restrict__ comb,
    const float* __restrict__ w, float* __restrict__ P)
{
    __shared__ __align__(16) float at[64 * 65];
    __shared__ __align__(16) float wt[64 * 65];
    int bc = blockIdx.x;   // 0..15 row chunk
    int kc = blockIdx.y;   // 0..7  k chunk
    int tid = threadIdx.x;
    int tx = tid & 15, ty = tid >> 4;
    float acc[4][4];
#pragma unroll
    for (int i = 0; i < 4; i++)
#pragma unroll
        for (int j = 0; j < 4; j++) acc[i][j] = 0.f;
    int b0 = bc * 64;
    for (int kt = 0; kt < 32; ++kt) {
        int k0 = kc * 2048 + kt * 64;
        __syncthreads();
        for (int i = tid; i < 4096; i += 256) {
            int r = i >> 6, kk = i & 63;
            at[r * 65 + kk] = comb[(size_t)(b0 + r) * 16384 + k0 + kk];
            wt[r * 65 + kk] = w[(size_t)r * 16384 + k0 + kk];
        }
        __syncthreads();
#pragma unroll 8
        for (int kk = 0; kk < 64; kk++) {
            float av[4], wv[4];
#pragma unroll
            for (int i = 0; i < 4; i++) av[i] = at[(ty * 4 + i) * 65 + kk];
#pragma unroll
            for (int j = 0; j < 4; j++) wv[j] = wt[(tx * 4 + j) * 65 + kk];
#pragma unroll
            for (int i = 0; i < 4; i++)
#pragma unroll
                for (int j = 0; j < 4; j++) acc[i][j] = fmaf(av[i], wv[j], acc[i][j]);
        }
    }
    float* Pp = P + (size_t)kc * 65536;
#pragma unroll
    for (int i = 0; i < 4; i++)
#pragma unroll
        for (int j = 0; j < 4; j++)
            Pp[(size_t)(b0 + ty * 4 + i) * 64 + tx * 4 + j] = acc[i][j];
}

// ---------------- reduce partials + bias + relu + fc2 ----------------
__global__ __launch_bounds__(256) void fc2_kernel(const float* __restrict__ P,
    const float* __restrict__ f1b, const float* __restrict__ w2, const float* __restrict__ b2,
    float* __restrict__ out)
{
    int b = blockIdx.x * 256 + threadIdx.x;  // 0..1023
    float z[64];
#pragma unroll
    for (int n = 0; n < 64; n++) z[n] = 0.f;
    for (int kc = 0; kc < 8; kc++) {
        const float* Pp = P + (size_t)kc * 65536 + (size_t)b * 64;
#pragma unroll
        for (int n = 0; n < 64; n++) z[n] += Pp[n];
    }
    float o[5] = {0.f, 0.f, 0.f, 0.f, 0.f};
#pragma unroll
    for (int n = 0; n < 64; n++) {
        float zz = fmaxf(z[n] + f1b[n], 0.f);
#pragma unroll
        for (int c = 0; c < 5; c++) o[c] = fmaf(zz, w2[c * 64 + n], o[c]);
    }
#pragma unroll
    for (int c = 0; c < 5; c++) out[b * 5 + c] = o[c] + b2[c];
}

extern "C" void kernel_launch(void* const* d_in, const int* in_sizes, int n_in,
                              void* d_out, int out_size, void* d_ws, size_t ws_size,
                              hipStream_t stream)
{
    const float* x   = (const float*)d_in[0];
    const float* c1w = (const float*)d_in[1];
    const float* c1b = (const float*)d_in[2];
    const float* ew1 = (const float*)d_in[3];
    const float* eb1 = (const float*)d_in[4];
    const float* g1  = (const float*)d_in[5];
    const float* bb1 = (const float*)d_in[6];
    const float* m1  = (const float*)d_in[7];
    const float* v1  = (const float*)d_in[8];
    const float* ew2 = (const float*)d_in[9];
    const float* eb2 = (const float*)d_in[10];
    const float* g2  = (const float*)d_in[11];
    const float* bb2 = (const float*)d_in[12];
    const float* m2  = (const float*)d_in[13];
    const float* v2  = (const float*)d_in[14];
    const float* ew3 = (const float*)d_in[15];
    const float* eb3 = (const float*)d_in[16];
    const float* g3  = (const float*)d_in[17];
    const float* bb3 = (const float*)d_in[18];
    const float* m3  = (const float*)d_in[19];
    const float* v3  = (const float*)d_in[20];
    const float* rw  = (const float*)d_in[21];
    const float* rb  = (const float*)d_in[22];
    const float* f1w = (const float*)d_in[23];
    const float* f1b = (const float*)d_in[24];
    const float* f2w = (const float*)d_in[25];
    const float* f2b = (const float*)d_in[26];

    float* ws     = (float*)d_ws;
    float* pooled = ws + OFF_POOLED;
    int*   tidx   = (int*)(ws + OFF_TOPKI);
    float* tg     = ws + OFF_TOPKG;
    float* b1p    = ws + OFF_B1;
    float* b2p    = ws + OFF_B2;
    float* b3p    = ws + OFF_B3;
    float* w1p    = ws + OFF_W1P;
    float* w2p    = ws + OFF_W2P;
    float* w3p    = ws + OFF_W3P;
    float* comb   = ws + OFF_COMB;
    float* P      = ws + OFF_P;
    float* out    = (float*)d_out;

    hipLaunchKernelGGL(pool_kernel, dim3(1024), dim3(256), 0, stream, x, c1w, c1b, pooled);
    hipLaunchKernelGGL(repack_kernel, dim3(170), dim3(256), 0, stream,
                       ew1, eb1, g1, bb1, m1, v1, ew2, eb2, g2, bb2, m2, v2,
                       ew3, eb3, g3, bb3, m3, v3, w1p, w2p, w3p, b1p, b2p, b3p);
    hipLaunchKernelGGL(router_kernel, dim3(1), dim3(1024), 0, stream, pooled, rw, rb, tidx, tg, out + 5120);
    hipLaunchKernelGGL(expert_kernel, dim3(4096), dim3(256), 0, stream,
                       x, c1w, c1b, w1p, w2p, w3p, b1p, b2p, b3p, tidx, tg, comb);
    hipLaunchKernelGGL(fc1_kernel, dim3(16, 8), dim3(256), 0, stream, comb, f1w, P);
    hipLaunchKernelGGL(fc2_kernel, dim3(4), dim3(256), 0, stream, P, f1b, f2w, f2b, out);
}

// Round 3
// 530.459 us; speedup vs baseline: 2.3595x; 1.3672x over previous
//
#include <hip/hip_runtime.h>

// ---------------- workspace layout (float offsets) ----------------
constexpr int L0 = 2048;
constexpr size_t OFF_POOLED = 0;                  // 1024*8
constexpr size_t OFF_TOPKI  = 8192;               // 2048 ints
constexpr size_t OFF_TOPKG  = 10240;              // 2048 floats
constexpr size_t OFF_B1     = 12288;              // 64
constexpr size_t OFF_B2     = 12352;              // 128
constexpr size_t OFF_B3     = 12480;              // 256
constexpr size_t OFF_W1P    = 12800;              // 2048  [e][ci8][co16][4]
constexpr size_t OFF_W2P    = 14848;              // 8192  [e][ci16][co32][4]
constexpr size_t OFF_W3P    = 23040;              // 32768 [e][ci32][co64][4]
constexpr size_t OFF_COMB   = 57344;              // 1024*16384
constexpr size_t OFF_P      = 57344 + 16777216;   // 8*1024*64

// ---------------- pooling kernel: pooled[b,c] = mean_l relu(conv1(x)) ----------------
__global__ __launch_bounds__(256) void pool_kernel(const float* __restrict__ x,
    const float* __restrict__ c1w, const float* __restrict__ c1b, float* __restrict__ pooled)
{
    __shared__ float xbuf[2050];
    __shared__ float red[8 * 256];
    int b = blockIdx.x, tid = threadIdx.x;
    const float* xr = x + (size_t)b * L0;
    for (int i = tid; i < 2050; i += 256) xbuf[i] = (i >= 1 && i <= L0) ? xr[i - 1] : 0.f;
    __syncthreads();
    float w[24], bb[8];
#pragma unroll
    for (int i = 0; i < 24; i++) w[i] = c1w[i];
#pragma unroll
    for (int c = 0; c < 8; c++) bb[c] = c1b[c];
    float acc[8];
#pragma unroll
    for (int c = 0; c < 8; c++) acc[c] = 0.f;
    for (int l = tid; l < L0; l += 256) {
        float xm = xbuf[l], x0 = xbuf[l + 1], xp = xbuf[l + 2];
#pragma unroll
        for (int c = 0; c < 8; c++)
            acc[c] += fmaxf(fmaf(w[3 * c], xm, fmaf(w[3 * c + 1], x0, fmaf(w[3 * c + 2], xp, bb[c]))), 0.f);
    }
#pragma unroll
    for (int c = 0; c < 8; c++) red[c * 256 + tid] = acc[c];
    __syncthreads();
    for (int off = 128; off > 0; off >>= 1) {
        if (tid < off) {
#pragma unroll
            for (int c = 0; c < 8; c++) red[c * 256 + tid] += red[c * 256 + tid + off];
        }
        __syncthreads();
    }
    if (tid < 8) pooled[b * 8 + tid] = red[tid * 256] * (1.f / L0);
}

// ---------------- weight repack + BN fold ----------------
__global__ __launch_bounds__(256) void repack_kernel(
    const float* __restrict__ ew1, const float* __restrict__ eb1, const float* __restrict__ g1,
    const float* __restrict__ bb1, const float* __restrict__ m1, const float* __restrict__ v1,
    const float* __restrict__ ew2, const float* __restrict__ eb2, const float* __restrict__ g2,
    const float* __restrict__ bb2, const float* __restrict__ m2, const float* __restrict__ v2,
    const float* __restrict__ ew3, const float* __restrict__ eb3, const float* __restrict__ g3,
    const float* __restrict__ bb3, const float* __restrict__ m3, const float* __restrict__ v3,
    float* __restrict__ w1p, float* __restrict__ w2p, float* __restrict__ w3p,
    float* __restrict__ b1p, float* __restrict__ b2p, float* __restrict__ b3p)
{
    int i = blockIdx.x * 256 + threadIdx.x;
    if (i < 2048) {
        int k = i & 3, r = i >> 2;
        int co = r & 15, r2 = r >> 4;
        int ci = r2 & 7, e = r2 >> 3;
        int ec = e * 16 + co;
        float A = g1[ec] * rsqrtf(v1[ec] + 1e-5f);
        w1p[i] = (k < 3) ? ew1[(ec * 8 + ci) * 3 + k] * A : 0.f;
    } else if (i < 10240) {
        int ii = i - 2048;
        int k = ii & 3, r = ii >> 2;
        int co = r & 31, r2 = r >> 5;
        int ci = r2 & 15, e = r2 >> 4;
        int ec = e * 32 + co;
        float A = g2[ec] * rsqrtf(v2[ec] + 1e-5f);
        w2p[ii] = (k < 3) ? ew2[(ec * 16 + ci) * 3 + k] * A : 0.f;
    } else if (i < 43008) {
        int ii = i - 10240;
        int k = ii & 3, r = ii >> 2;
        int co = r & 63, r2 = r >> 6;
        int ci = r2 & 31, e = r2 >> 5;
        int ec = e * 64 + co;
        float A = g3[ec] * rsqrtf(v3[ec] + 1e-5f);
        w3p[ii] = (k < 3) ? ew3[(ec * 32 + ci) * 3 + k] * A : 0.f;
    } else if (i < 43456) {
        int j = i - 43008;
        if (j < 64)       { float A = g1[j] * rsqrtf(v1[j] + 1e-5f); b1p[j] = fmaf(eb1[j] - m1[j], A, bb1[j]); }
        else if (j < 192) { int q = j - 64;  float A = g2[q] * rsqrtf(v2[q] + 1e-5f); b2p[q] = fmaf(eb2[q] - m2[q], A, bb2[q]); }
        else              { int q = j - 192; float A = g3[q] * rsqrtf(v3[q] + 1e-5f); b3p[q] = fmaf(eb3[q] - m3[q], A, bb3[q]); }
    }
}

// ---------------- router: softmax, top-2, gates, aux loss ----------------
__global__ __launch_bounds__(1024) void router_kernel(const float* __restrict__ pooled,
    const float* __restrict__ rw, const float* __restrict__ rb,
    int* __restrict__ tidx, float* __restrict__ tg, float* __restrict__ aux)
{
    __shared__ float pr[4][1024];
    int b = threadIdx.x;
    float p[8];
#pragma unroll
    for (int c = 0; c < 8; c++) p[c] = pooled[b * 8 + c];
    float lg[4];
#pragma unroll
    for (int e = 0; e < 4; e++) {
        float a = rb[e];
#pragma unroll
        for (int c = 0; c < 8; c++) a = fmaf(p[c], rw[e * 8 + c], a);
        lg[e] = a;
    }
    float m = fmaxf(fmaxf(lg[0], lg[1]), fmaxf(lg[2], lg[3]));
    float pe[4]; float s = 0.f;
#pragma unroll
    for (int e = 0; e < 4; e++) { pe[e] = expf(lg[e] - m); s += pe[e]; }
    float inv = 1.f / s;
#pragma unroll
    for (int e = 0; e < 4; e++) pe[e] *= inv;
    int e0 = 0;
#pragma unroll
    for (int e = 1; e < 4; e++) if (pe[e] > pe[e0]) e0 = e;
    int e1 = -1;
#pragma unroll
    for (int e = 0; e < 4; e++) if (e != e0 && (e1 < 0 || pe[e] > pe[e1])) e1 = e;
    float s2 = pe[e0] + pe[e1];
    tidx[b * 2] = e0; tidx[b * 2 + 1] = e1;
    tg[b * 2] = pe[e0] / s2; tg[b * 2 + 1] = pe[e1] / s2;
#pragma unroll
    for (int e = 0; e < 4; e++) pr[e][b] = pe[e];
    __syncthreads();
    for (int off = 512; off > 0; off >>= 1) {
        if (b < off) {
#pragma unroll
            for (int e = 0; e < 4; e++) pr[e][b] += pr[e][b + off];
        }
        __syncthreads();
    }
    if (b == 0) {
        float mp[4]; float mm = 0.f;
#pragma unroll
        for (int e = 0; e < 4; e++) { mp[e] = pr[e][0] * (1.f / 1024.f); mm += mp[e]; }
        mm *= 0.25f;
        float var = 0.f;
#pragma unroll
        for (int e = 0; e < 4; e++) { float d = mp[e] - mm; var += d * d; }
        var *= (1.f / 3.f);
        float cv = sqrtf(var) / (mm + 1e-10f);
        aux[0] = cv * cv;
    }
}

// ---------------- expert chain ----------------
// LDS layout (floats), even/odd split buffers: E[k]=v[2k], O[k]=v[2k+1]
constexpr int XB_OFF = 0;      // [528]
constexpr int E0_OFF = 528;    // 8 x 268
constexpr int O0_OFF = 2672;   // 8 x 268
constexpr int E1_OFF = 4816;   // 16 x 132
constexpr int O1_OFF = 6928;   // 16 x 132
constexpr int E2_OFF = 9040;   // 32 x 68
constexpr int O2_OFF = 11216;  // 32 x 68
constexpr int LDS_FLOATS = 13392;

// Pool-stage: conv k=3 'same' + (folded BN) + relu + maxpool2, even/odd split in/out.
// Thread: 4 output channels (co0=4*(tid&(NCQ-1))) x 4 positions (j0=4*(tid>>PSH)+pass*PSTRIDE).
template<int CI, int NCQ, int SIN, int SOUT, int LOUT, int PSTRIDE>
__device__ __forceinline__ void stage_pool(
    const float* __restrict__ wp,   // [CI][CO][4], BN-folded, this expert
    const float* __restrict__ bp,   // [CO]
    const float* __restrict__ Ein, const float* __restrict__ Oin,
    float* __restrict__ Eout, float* __restrict__ Oout,
    int a_out, int tid, int npass)
{
    constexpr int PSH = (NCQ == 4) ? 2 : 3;
    constexpr int CO = NCQ * 4;
    const int cq = tid & (NCQ - 1);
    const int pg = tid >> PSH;
    const int co0 = 4 * cq;
    const float4 bias = *reinterpret_cast<const float4*>(bp + co0);
    for (int ps = 0; ps < npass; ++ps) {
        const int j0 = 4 * pg + ps * PSTRIDE;
        float aE[4][4], aO[4][4];
#pragma unroll
        for (int p = 0; p < 4; ++p) {
            aE[0][p] = bias.x; aO[0][p] = bias.x;
            aE[1][p] = bias.y; aO[1][p] = bias.y;
            aE[2][p] = bias.z; aO[2][p] = bias.z;
            aE[3][p] = bias.w; aO[3][p] = bias.w;
        }
#pragma unroll 4
        for (int ci = 0; ci < CI; ++ci) {
            const float* wb = wp + (ci * CO + co0) * 4;
            float4 wv0 = *reinterpret_cast<const float4*>(wb);
            float4 wv1 = *reinterpret_cast<const float4*>(wb + 4);
            float4 wv2 = *reinterpret_cast<const float4*>(wb + 8);
            float4 wv3 = *reinterpret_cast<const float4*>(wb + 12);
            const float* ep = Ein + ci * SIN + j0;
            float4 ev = *reinterpret_cast<const float4*>(ep);
            float e4s = ep[4];
            const float* op = Oin + ci * SIN + j0;
            float4 ov = *reinterpret_cast<const float4*>(op);
            float o4s = op[4];
#define DO_C(c, W) \
            aE[c][0] = fmaf(W.x, ev.x, fmaf(W.y, ov.x, fmaf(W.z, ev.y, aE[c][0]))); \
            aO[c][0] = fmaf(W.x, ov.x, fmaf(W.y, ev.y, fmaf(W.z, ov.y, aO[c][0]))); \
            aE[c][1] = fmaf(W.x, ev.y, fmaf(W.y, ov.y, fmaf(W.z, ev.z, aE[c][1]))); \
            aO[c][1] = fmaf(W.x, ov.y, fmaf(W.y, ev.z, fmaf(W.z, ov.z, aO[c][1]))); \
            aE[c][2] = fmaf(W.x, ev.z, fmaf(W.y, ov.z, fmaf(W.z, ev.w, aE[c][2]))); \
            aO[c][2] = fmaf(W.x, ov.z, fmaf(W.y, ev.w, fmaf(W.z, ov.w, aO[c][2]))); \
            aE[c][3] = fmaf(W.x, ev.w, fmaf(W.y, ov.w, fmaf(W.z, e4s, aE[c][3]))); \
            aO[c][3] = fmaf(W.x, ov.w, fmaf(W.y, e4s, fmaf(W.z, o4s, aO[c][3])));
            DO_C(0, wv0) DO_C(1, wv1) DO_C(2, wv2) DO_C(3, wv3)
#undef DO_C
        }
#pragma unroll
        for (int c = 0; c < 4; ++c) {
            float v[4];
#pragma unroll
            for (int p = 0; p < 4; ++p) {
                int l = a_out + j0 + p;
                float mv = fmaxf(aE[c][p], aO[c][p]);
                v[p] = (l >= 0 && l < LOUT) ? fmaxf(mv, 0.f) : 0.f;
            }
            float* eo = Eout + (co0 + c) * SOUT + (j0 >> 1);
            *reinterpret_cast<float2*>(eo) = make_float2(v[0], v[2]);
            float* oo = Oout + (co0 + c) * SOUT + (j0 >> 1);
            *reinterpret_cast<float2*>(oo) = make_float2(v[1], v[3]);
        }
    }
}

__global__ __launch_bounds__(256, 3) void expert_kernel(
    const float* __restrict__ x, const float* __restrict__ c1w, const float* __restrict__ c1b,
    const float* __restrict__ w1p, const float* __restrict__ w2p, const float* __restrict__ w3p,
    const float* __restrict__ b1p, const float* __restrict__ b2p, const float* __restrict__ b3p,
    const int* __restrict__ tidx, const float* __restrict__ tg,
    float* __restrict__ comb)
{
    __shared__ __align__(16) float lds[LDS_FLOATS];
    const int tid = threadIdx.x;
    const int bt = blockIdx.x;
    const int b = bt >> 2, t = bt & 3;
    const int a3 = t * 64, a2 = 2 * a3 - 1, a1 = 4 * a3 - 3, a0 = 8 * a3 - 7;
    const float* xr = x + (size_t)b * L0;
    float* xb = lds + XB_OFF;
    // load raw x tile: xb[m] = x[a0-1+m], m in [0,528)
    for (int m = tid; m < 528; m += 256) {
        int g = a0 - 1 + m;
        xb[m] = (g >= 0 && g < L0) ? xr[g] : 0.f;
    }
    __syncthreads();
    // stage0: conv1+relu -> E0/O0, outputs j in [0,526), l0 = a0 + j
    {
        const int ch = tid & 7;
        const int pj = tid >> 3;    // 0..31, parity fixed per thread
        float wa = c1w[ch * 3], wb = c1w[ch * 3 + 1], wc = c1w[ch * 3 + 2], bb = c1b[ch];
        float* tgt = lds + ((pj & 1) ? O0_OFF : E0_OFF) + ch * 268;
        const int kb = pj >> 1;
        for (int k = 0; k < 17; ++k) {
            int j = pj + 32 * k;
            if (j >= 526) break;
            int l = a0 + j;
            float v = 0.f;
            if (l >= 0 && l < L0)
                v = fmaxf(fmaf(wa, xb[j], fmaf(wb, xb[j + 1], fmaf(wc, xb[j + 2], bb))), 0.f);
            tgt[kb + 16 * k] = v;
        }
    }
    const int pg1 = tid >> 2; const int np1 = (pg1 >= 62) ? 2 : 1;
    const int pg2 = tid >> 3; const int np2 = (pg2 == 31) ? 2 : 1;
    const int ea = tidx[b * 2], eb = tidx[b * 2 + 1];
    const float ga = tg[b * 2], gb = tg[b * 2 + 1];
    // stage3 thread geometry: cq = tid>>4 (co-quad), pg = tid&15 (pos-group) -> coalesced comb
    const int cq3 = tid >> 4, pg3 = tid & 15;
    const int co03 = 4 * cq3, j03 = 4 * pg3;
    float oa[4][4];
#pragma unroll
    for (int c = 0; c < 4; c++)
#pragma unroll
        for (int p = 0; p < 4; p++) oa[c][p] = 0.f;
#pragma unroll 1
    for (int slot = 0; slot < 2; ++slot) {
        const int e = slot ? eb : ea;
        const float g = slot ? gb : ga;
        __syncthreads();  // E0/O0 ready (slot0) / prev-slot E1 readers done
        stage_pool<8, 4, 268, 132, 1024, 8>(w1p + e * 512, b1p + e * 16,
            lds + E0_OFF, lds + O0_OFF, lds + E1_OFF, lds + O1_OFF, a1, tid, np1);
        __syncthreads();
        stage_pool<16, 8, 132, 68, 512, 4>(w2p + e * 2048, b2p + e * 32,
            lds + E1_OFF, lds + O1_OFF, lds + E2_OFF, lds + O2_OFF, a2, tid, np2);
        __syncthreads();
        // stage3: CI=32, CO=64, 16x16 exact, accumulate gated into regs
        {
            const float* wp = w3p + e * 8192;
            const float* bp = b3p + e * 64;
            const float4 bias = *reinterpret_cast<const float4*>(bp + co03);
            float aE[4][4], aO[4][4];
#pragma unroll
            for (int p = 0; p < 4; ++p) {
                aE[0][p] = bias.x; aO[0][p] = bias.x;
                aE[1][p] = bias.y; aO[1][p] = bias.y;
                aE[2][p] = bias.z; aO[2][p] = bias.z;
                aE[3][p] = bias.w; aO[3][p] = bias.w;
            }
            const float* Ein = lds + E2_OFF;
            const float* Oin = lds + O2_OFF;
#pragma unroll 4
            for (int ci = 0; ci < 32; ++ci) {
                const float* wb = wp + (ci * 64 + co03) * 4;
                float4 wv0 = *reinterpret_cast<const float4*>(wb);
                float4 wv1 = *reinterpret_cast<const float4*>(wb + 4);
                float4 wv2 = *reinterpret_cast<const float4*>(wb + 8);
                float4 wv3 = *reinterpret_cast<const float4*>(wb + 12);
                const float* ep = Ein + ci * 68 + j03;
                float4 ev = *reinterpret_cast<const float4*>(ep);
                float e4s = ep[4];
                const float* op = Oin + ci * 68 + j03;
                float4 ov = *reinterpret_cast<const float4*>(op);
                float o4s = op[4];
#define DO_C(c, W) \
                aE[c][0] = fmaf(W.x, ev.x, fmaf(W.y, ov.x, fmaf(W.z, ev.y, aE[c][0]))); \
                aO[c][0] = fmaf(W.x, ov.x, fmaf(W.y, ev.y, fmaf(W.z, ov.y, aO[c][0]))); \
                aE[c][1] = fmaf(W.x, ev.y, fmaf(W.y, ov.y, fmaf(W.z, ev.z, aE[c][1]))); \
                aO[c][1] = fmaf(W.x, ov.y, fmaf(W.y, ev.z, fmaf(W.z, ov.z, aO[c][1]))); \
                aE[c][2] = fmaf(W.x, ev.z, fmaf(W.y, ov.z, fmaf(W.z, ev.w, aE[c][2]))); \
                aO[c][2] = fmaf(W.x, ov.z, fmaf(W.y, ev.w, fmaf(W.z, ov.w, aO[c][2]))); \
                aE[c][3] = fmaf(W.x, ev.w, fmaf(W.y, ov.w, fmaf(W.z, e4s, aE[c][3]))); \
                aO[c][3] = fmaf(W.x, ov.w, fmaf(W.y, e4s, fmaf(W.z, o4s, aO[c][3])));
                DO_C(0, wv0) DO_C(1, wv1) DO_C(2, wv2) DO_C(3, wv3)
#undef DO_C
            }
#pragma unroll
            for (int c = 0; c < 4; ++c)
#pragma unroll
                for (int p = 0; p < 4; ++p)
                    oa[c][p] = fmaf(g, fmaxf(fmaxf(aE[c][p], aO[c][p]), 0.f), oa[c][p]);
        }
    }
    // write gated combined output: comb[b][co][a3 + j], coalesced float4 over pg3
    float* cb = comb + (size_t)b * 16384 + (size_t)co03 * 256 + a3 + j03;
#pragma unroll
    for (int c = 0; c < 4; ++c)
        *reinterpret_cast<float4*>(cb + c * 256) = make_float4(oa[c][0], oa[c][1], oa[c][2], oa[c][3]);
}

// ---------------- fc1 split-K GEMM: P[kc][b][64] = partial(flat @ fc1_w.T) ----------------
__global__ __launch_bounds__(256) void fc1_kernel(const float* __restrict__ comb,
    const float* __restrict__ w, float* __restrict__ P)
{
    __shared__ __align__(16) float at[64 * 65];
    __shared__ __align__(16) float wt[64 * 65];
    int bc = blockIdx.x;   // 0..15 row chunk
    int kc = blockIdx.y;   // 0..7  k chunk
    int tid = threadIdx.x;
    int tx = tid & 15, ty = tid >> 4;
    float acc[4][4];
#pragma unroll
    for (int i = 0; i < 4; i++)
#pragma unroll
        for (int j = 0; j < 4; j++) acc[i][j] = 0.f;
    int b0 = bc * 64;
    for (int kt = 0; kt < 32; ++kt) {
        int k0 = kc * 2048 + kt * 64;
        __syncthreads();
        for (int i = tid; i < 4096; i += 256) {
            int r = i >> 6, kk = i & 63;
            at[r * 65 + kk] = comb[(size_t)(b0 + r) * 16384 + k0 + kk];
            wt[r * 65 + kk] = w[(size_t)r * 16384 + k0 + kk];
        }
        __syncthreads();
#pragma unroll 8
        for (int kk = 0; kk < 64; kk++) {
            float av[4], wv[4];
#pragma unroll
            for (int i = 0; i < 4; i++) av[i] = at[(ty * 4 + i) * 65 + kk];
#pragma unroll
            for (int j = 0; j < 4; j++) wv[j] = wt[(tx * 4 + j) * 65 + kk];
#pragma unroll
            for (int i = 0; i < 4; i++)
#pragma unroll
                for (int j = 0; j < 4; j++) acc[i][j] = fmaf(av[i], wv[j], acc[i][j]);
        }
    }
    float* Pp = P + (size_t)kc * 65536;
#pragma unroll
    for (int i = 0; i < 4; i++)
#pragma unroll
        for (int j = 0; j < 4; j++)
            Pp[(size_t)(b0 + ty * 4 + i) * 64 + tx * 4 + j] = acc[i][j];
}

// ---------------- reduce partials + bias + relu + fc2 ----------------
__global__ __launch_bounds__(256) void fc2_kernel(const float* __restrict__ P,
    const float* __restrict__ f1b, const float* __restrict__ w2, const float* __restrict__ b2,
    float* __restrict__ out)
{
    int b = blockIdx.x * 256 + threadIdx.x;  // 0..1023
    float z[64];
#pragma unroll
    for (int n = 0; n < 64; n++) z[n] = 0.f;
    for (int kc = 0; kc < 8; kc++) {
        const float* Pp = P + (size_t)kc * 65536 + (size_t)b * 64;
#pragma unroll
        for (int n = 0; n < 64; n++) z[n] += Pp[n];
    }
    float o[5] = {0.f, 0.f, 0.f, 0.f, 0.f};
#pragma unroll
    for (int n = 0; n < 64; n++) {
        float zz = fmaxf(z[n] + f1b[n], 0.f);
#pragma unroll
        for (int c = 0; c < 5; c++) o[c] = fmaf(zz, w2[c * 64 + n], o[c]);
    }
#pragma unroll
    for (int c = 0; c < 5; c++) out[b * 5 + c] = o[c] + b2[c];
}

extern "C" void kernel_launch(void* const* d_in, const int* in_sizes, int n_in,
                              void* d_out, int out_size, void* d_ws, size_t ws_size,
                              hipStream_t stream)
{
    const float* x   = (const float*)d_in[0];
    const float* c1w = (const float*)d_in[1];
    const float* c1b = (const float*)d_in[2];
    const float* ew1 = (const float*)d_in[3];
    const float* eb1 = (const float*)d_in[4];
    const float* g1  = (const float*)d_in[5];
    const float* bb1 = (const float*)d_in[6];
    const float* m1  = (const float*)d_in[7];
    const float* v1  = (const float*)d_in[8];
    const float* ew2 = (const float*)d_in[9];
    const float* eb2 = (const float*)d_in[10];
    const float* g2  = (const float*)d_in[11];
    const float* bb2 = (const float*)d_in[12];
    const float* m2  = (const float*)d_in[13];
    const float* v2  = (const float*)d_in[14];
    const float* ew3 = (const float*)d_in[15];
    const float* eb3 = (const float*)d_in[16];
    const float* g3  = (const float*)d_in[17];
    const float* bb3 = (const float*)d_in[18];
    const float* m3  = (const float*)d_in[19];
    const float* v3  = (const float*)d_in[20];
    const float* rw  = (const float*)d_in[21];
    const float* rb  = (const float*)d_in[22];
    const float* f1w = (const float*)d_in[23];
    const float* f1b = (const float*)d_in[24];
    const float* f2w = (const float*)d_in[25];
    const float* f2b = (const float*)d_in[26];

    float* ws     = (float*)d_ws;
    float* pooled = ws + OFF_POOLED;
    int*   tidx   = (int*)(ws + OFF_TOPKI);
    float* tg     = ws + OFF_TOPKG;
    float* b1p    = ws + OFF_B1;
    float* b2p    = ws + OFF_B2;
    float* b3p    = ws + OFF_B3;
    float* w1p    = ws + OFF_W1P;
    float* w2p    = ws + OFF_W2P;
    float* w3p    = ws + OFF_W3P;
    float* comb   = ws + OFF_COMB;
    float* P      = ws + OFF_P;
    float* out    = (float*)d_out;

    hipLaunchKernelGGL(pool_kernel, dim3(1024), dim3(256), 0, stream, x, c1w, c1b, pooled);
    hipLaunchKernelGGL(repack_kernel, dim3(170), dim3(256), 0, stream,
                       ew1, eb1, g1, bb1, m1, v1, ew2, eb2, g2, bb2, m2, v2,
                       ew3, eb3, g3, bb3, m3, v3, w1p, w2p, w3p, b1p, b2p, b3p);
    hipLaunchKernelGGL(router_kernel, dim3(1), dim3(1024), 0, stream, pooled, rw, rb, tidx, tg, out + 5120);
    hipLaunchKernelGGL(expert_kernel, dim3(4096), dim3(256), 0, stream,
                       x, c1w, c1b, w1p, w2p, w3p, b1p, b2p, b3p, tidx, tg, comb);
    hipLaunchKernelGGL(fc1_kernel, dim3(16, 8), dim3(256), 0, stream, comb, f1w, P);
    hipLaunchKernelGGL(fc2_kernel, dim3(4), dim3(256), 0, stream, P, f1b, f2w, f2b, out);
}

// Round 4
// 501.140 us; speedup vs baseline: 2.4976x; 1.0585x over previous
//
#include <hip/hip_runtime.h>

// ---------------- workspace layout (float offsets) ----------------
constexpr int L0 = 2048;
constexpr size_t OFF_POOLED = 0;                  // 1024*8
constexpr size_t OFF_TOPKI  = 8192;               // 2048 ints
constexpr size_t OFF_TOPKG  = 10240;              // 2048 floats
constexpr size_t OFF_B1     = 12288;              // 64
constexpr size_t OFF_B2     = 12352;              // 128
constexpr size_t OFF_B3     = 12480;              // 256
constexpr size_t OFF_W1P    = 12800;              // 2048  [e][ci8][co16][4]
constexpr size_t OFF_W2P    = 14848;              // 8192  [e][ci16][co32][4]
constexpr size_t OFF_W3P    = 23040;              // 32768 [e][ci32][co64][4]
constexpr size_t OFF_COMB   = 57344;              // 1024*16384
constexpr size_t OFF_P      = 57344 + 16777216;   // 8*1024*64

// ---------------- pooling kernel: pooled[b,c] = mean_l relu(conv1(x)) ----------------
__global__ __launch_bounds__(256) void pool_kernel(const float* __restrict__ x,
    const float* __restrict__ c1w, const float* __restrict__ c1b, float* __restrict__ pooled)
{
    __shared__ float xbuf[2050];
    __shared__ float red[8 * 256];
    int b = blockIdx.x, tid = threadIdx.x;
    const float* xr = x + (size_t)b * L0;
    for (int i = tid; i < 2050; i += 256) xbuf[i] = (i >= 1 && i <= L0) ? xr[i - 1] : 0.f;
    __syncthreads();
    float w[24], bb[8];
#pragma unroll
    for (int i = 0; i < 24; i++) w[i] = c1w[i];
#pragma unroll
    for (int c = 0; c < 8; c++) bb[c] = c1b[c];
    float acc[8];
#pragma unroll
    for (int c = 0; c < 8; c++) acc[c] = 0.f;
    for (int l = tid; l < L0; l += 256) {
        float xm = xbuf[l], x0 = xbuf[l + 1], xp = xbuf[l + 2];
#pragma unroll
        for (int c = 0; c < 8; c++)
            acc[c] += fmaxf(fmaf(w[3 * c], xm, fmaf(w[3 * c + 1], x0, fmaf(w[3 * c + 2], xp, bb[c]))), 0.f);
    }
#pragma unroll
    for (int c = 0; c < 8; c++) red[c * 256 + tid] = acc[c];
    __syncthreads();
    for (int off = 128; off > 0; off >>= 1) {
        if (tid < off) {
#pragma unroll
            for (int c = 0; c < 8; c++) red[c * 256 + tid] += red[c * 256 + tid + off];
        }
        __syncthreads();
    }
    if (tid < 8) pooled[b * 8 + tid] = red[tid * 256] * (1.f / L0);
}

// ---------------- weight repack + BN fold ----------------
__global__ __launch_bounds__(256) void repack_kernel(
    const float* __restrict__ ew1, const float* __restrict__ eb1, const float* __restrict__ g1,
    const float* __restrict__ bb1, const float* __restrict__ m1, const float* __restrict__ v1,
    const float* __restrict__ ew2, const float* __restrict__ eb2, const float* __restrict__ g2,
    const float* __restrict__ bb2, const float* __restrict__ m2, const float* __restrict__ v2,
    const float* __restrict__ ew3, const float* __restrict__ eb3, const float* __restrict__ g3,
    const float* __restrict__ bb3, const float* __restrict__ m3, const float* __restrict__ v3,
    float* __restrict__ w1p, float* __restrict__ w2p, float* __restrict__ w3p,
    float* __restrict__ b1p, float* __restrict__ b2p, float* __restrict__ b3p)
{
    int i = blockIdx.x * 256 + threadIdx.x;
    if (i < 2048) {
        int k = i & 3, r = i >> 2;
        int co = r & 15, r2 = r >> 4;
        int ci = r2 & 7, e = r2 >> 3;
        int ec = e * 16 + co;
        float A = g1[ec] * rsqrtf(v1[ec] + 1e-5f);
        w1p[i] = (k < 3) ? ew1[(ec * 8 + ci) * 3 + k] * A : 0.f;
    } else if (i < 10240) {
        int ii = i - 2048;
        int k = ii & 3, r = ii >> 2;
        int co = r & 31, r2 = r >> 5;
        int ci = r2 & 15, e = r2 >> 4;
        int ec = e * 32 + co;
        float A = g2[ec] * rsqrtf(v2[ec] + 1e-5f);
        w2p[ii] = (k < 3) ? ew2[(ec * 16 + ci) * 3 + k] * A : 0.f;
    } else if (i < 43008) {
        int ii = i - 10240;
        int k = ii & 3, r = ii >> 2;
        int co = r & 63, r2 = r >> 6;
        int ci = r2 & 31, e = r2 >> 5;
        int ec = e * 64 + co;
        float A = g3[ec] * rsqrtf(v3[ec] + 1e-5f);
        w3p[ii] = (k < 3) ? ew3[(ec * 32 + ci) * 3 + k] * A : 0.f;
    } else if (i < 43456) {
        int j = i - 43008;
        if (j < 64)       { float A = g1[j] * rsqrtf(v1[j] + 1e-5f); b1p[j] = fmaf(eb1[j] - m1[j], A, bb1[j]); }
        else if (j < 192) { int q = j - 64;  float A = g2[q] * rsqrtf(v2[q] + 1e-5f); b2p[q] = fmaf(eb2[q] - m2[q], A, bb2[q]); }
        else              { int q = j - 192; float A = g3[q] * rsqrtf(v3[q] + 1e-5f); b3p[q] = fmaf(eb3[q] - m3[q], A, bb3[q]); }
    }
}

// ---------------- router: softmax, top-2, gates, aux loss ----------------
__global__ __launch_bounds__(1024) void router_kernel(const float* __restrict__ pooled,
    const float* __restrict__ rw, const float* __restrict__ rb,
    int* __restrict__ tidx, float* __restrict__ tg, float* __restrict__ aux)
{
    __shared__ float pr[4][1024];
    int b = threadIdx.x;
    float p[8];
#pragma unroll
    for (int c = 0; c < 8; c++) p[c] = pooled[b * 8 + c];
    float lg[4];
#pragma unroll
    for (int e = 0; e < 4; e++) {
        float a = rb[e];
#pragma unroll
        for (int c = 0; c < 8; c++) a = fmaf(p[c], rw[e * 8 + c], a);
        lg[e] = a;
    }
    float m = fmaxf(fmaxf(lg[0], lg[1]), fmaxf(lg[2], lg[3]));
    float pe[4]; float s = 0.f;
#pragma unroll
    for (int e = 0; e < 4; e++) { pe[e] = expf(lg[e] - m); s += pe[e]; }
    float inv = 1.f / s;
#pragma unroll
    for (int e = 0; e < 4; e++) pe[e] *= inv;
    int e0 = 0;
#pragma unroll
    for (int e = 1; e < 4; e++) if (pe[e] > pe[e0]) e0 = e;
    int e1 = -1;
#pragma unroll
    for (int e = 0; e < 4; e++) if (e != e0 && (e1 < 0 || pe[e] > pe[e1])) e1 = e;
    float s2 = pe[e0] + pe[e1];
    tidx[b * 2] = e0; tidx[b * 2 + 1] = e1;
    tg[b * 2] = pe[e0] / s2; tg[b * 2 + 1] = pe[e1] / s2;
#pragma unroll
    for (int e = 0; e < 4; e++) pr[e][b] = pe[e];
    __syncthreads();
    for (int off = 512; off > 0; off >>= 1) {
        if (b < off) {
#pragma unroll
            for (int e = 0; e < 4; e++) pr[e][b] += pr[e][b + off];
        }
        __syncthreads();
    }
    if (b == 0) {
        float mp[4]; float mm = 0.f;
#pragma unroll
        for (int e = 0; e < 4; e++) { mp[e] = pr[e][0] * (1.f / 1024.f); mm += mp[e]; }
        mm *= 0.25f;
        float var = 0.f;
#pragma unroll
        for (int e = 0; e < 4; e++) { float d = mp[e] - mm; var += d * d; }
        var *= (1.f / 3.f);
        float cv = sqrtf(var) / (mm + 1e-10f);
        aux[0] = cv * cv;
    }
}

// ---------------- expert chain, T=32 final positions per block ----------------
// LDS layout (floats), even/odd split: E[k] = stage-out at rel j=2k, O[k] = j=2k+1
constexpr int XB_OFF = 0;      // 284 (pad 288)
constexpr int E0_OFF = 288;    // 8 x 148
constexpr int O0_OFF = 1472;   // 8 x 148
constexpr int E1_OFF = 2656;   // 16 x 76
constexpr int O1_OFF = 3872;   // 16 x 76
constexpr int E2_OFF = 5088;   // 32 x 36
constexpr int O2_OFF = 6240;   // 32 x 36
constexpr int LDS_FLOATS = 7392;   // 29568 B -> 5 blocks/CU

#define DO_C(c, W) \
    aE[c][0] = fmaf(W.x, ev.x, fmaf(W.y, ov.x, fmaf(W.z, ev.y, aE[c][0]))); \
    aO[c][0] = fmaf(W.x, ov.x, fmaf(W.y, ev.y, fmaf(W.z, ov.y, aO[c][0]))); \
    aE[c][1] = fmaf(W.x, ev.y, fmaf(W.y, ov.y, fmaf(W.z, ev.z, aE[c][1]))); \
    aO[c][1] = fmaf(W.x, ov.y, fmaf(W.y, ev.z, fmaf(W.z, ov.z, aO[c][1]))); \
    aE[c][2] = fmaf(W.x, ev.z, fmaf(W.y, ov.z, fmaf(W.z, ev.w, aE[c][2]))); \
    aO[c][2] = fmaf(W.x, ov.z, fmaf(W.y, ev.w, fmaf(W.z, ov.w, aO[c][2]))); \
    aE[c][3] = fmaf(W.x, ev.w, fmaf(W.y, ov.w, fmaf(W.z, e4, aE[c][3]))); \
    aO[c][3] = fmaf(W.x, ov.w, fmaf(W.y, e4, fmaf(W.z, o4, aO[c][3])));

// one pass: 2 output channels (co0, co0+1) x 4 positions (j0..j0+3)
template<int CI, int CO, int SIN, int SOUT, int LOUT, int JOUT, bool GUARD>
__device__ __forceinline__ void stage2ch(
    const float* __restrict__ wp, const float b0, const float b1,
    const float* __restrict__ Ein, const float* __restrict__ Oin,
    float* __restrict__ Eout, float* __restrict__ Oout,
    const int a_out, const int co0, const int j0)
{
    float aE[2][4], aO[2][4];
#pragma unroll
    for (int p = 0; p < 4; ++p) { aE[0][p] = b0; aO[0][p] = b0; aE[1][p] = b1; aO[1][p] = b1; }
#pragma unroll 4
    for (int ci = 0; ci < CI; ++ci) {
        const float* wb = wp + (ci * CO + co0) * 4;
        float4 w0 = *reinterpret_cast<const float4*>(wb);
        float4 w1 = *reinterpret_cast<const float4*>(wb + 4);
        const float* ep = Ein + ci * SIN + j0;
        float4 ev = *reinterpret_cast<const float4*>(ep);
        float e4 = ep[4];
        const float* op = Oin + ci * SIN + j0;
        float4 ov = *reinterpret_cast<const float4*>(op);
        float o4 = op[4];
        DO_C(0, w0) DO_C(1, w1)
    }
#pragma unroll
    for (int c = 0; c < 2; ++c) {
        float v[4];
#pragma unroll
        for (int p = 0; p < 4; ++p) {
            int l = a_out + j0 + p;
            bool ok = (l >= 0) && (l < LOUT);
            if (GUARD) ok = ok && (j0 + p < JOUT);
            v[p] = ok ? fmaxf(fmaxf(aE[c][p], aO[c][p]), 0.f) : 0.f;
        }
        *reinterpret_cast<float2*>(Eout + (co0 + c) * SOUT + (j0 >> 1)) = make_float2(v[0], v[2]);
        *reinterpret_cast<float2*>(Oout + (co0 + c) * SOUT + (j0 >> 1)) = make_float2(v[1], v[3]);
    }
}

// stage3 pass: 2ch x 4pos, gated accumulate into registers (no bounds guard needed)
__device__ __forceinline__ void stage3_2ch(
    const float* __restrict__ wp, const float b0, const float b1,
    const float* __restrict__ Ein, const float* __restrict__ Oin,
    const float g, float oa[2][4], const int co0, const int j0)
{
    float aE[2][4], aO[2][4];
#pragma unroll
    for (int p = 0; p < 4; ++p) { aE[0][p] = b0; aO[0][p] = b0; aE[1][p] = b1; aO[1][p] = b1; }
#pragma unroll 4
    for (int ci = 0; ci < 32; ++ci) {
        const float* wb = wp + (ci * 64 + co0) * 4;
        float4 w0 = *reinterpret_cast<const float4*>(wb);
        float4 w1 = *reinterpret_cast<const float4*>(wb + 4);
        const float* ep = Ein + ci * 36 + j0;
        float4 ev = *reinterpret_cast<const float4*>(ep);
        float e4 = ep[4];
        const float* op = Oin + ci * 36 + j0;
        float4 ov = *reinterpret_cast<const float4*>(op);
        float o4 = op[4];
        DO_C(0, w0) DO_C(1, w1)
    }
#pragma unroll
    for (int c = 0; c < 2; ++c)
#pragma unroll
        for (int p = 0; p < 4; ++p)
            oa[c][p] = fmaf(g, fmaxf(fmaxf(aE[c][p], aO[c][p]), 0.f), oa[c][p]);
}

__global__ __launch_bounds__(256, 5) void expert_kernel(
    const float* __restrict__ x, const float* __restrict__ c1w, const float* __restrict__ c1b,
    const float* __restrict__ w1p, const float* __restrict__ w2p, const float* __restrict__ w3p,
    const float* __restrict__ b1p, const float* __restrict__ b2p, const float* __restrict__ b3p,
    const int* __restrict__ tidx, const float* __restrict__ tg,
    float* __restrict__ comb)
{
    __shared__ __align__(16) float lds[LDS_FLOATS];
    const int tid = threadIdx.x;
    const int bt = blockIdx.x;
    const int b = bt >> 3, t = bt & 7;
    const int a3 = t * 32, a2 = 2 * a3 - 1, a1 = 4 * a3 - 3, a0 = 8 * a3 - 7;
    const float* xr = x + (size_t)b * L0;
    float* xb = lds + XB_OFF;
    // xb[m] = x[a0 - 1 + m], m in [0, 284)
    for (int m = tid; m < 284; m += 256) {
        int gpos = a0 - 1 + m;
        xb[m] = (gpos >= 0 && gpos < L0) ? xr[gpos] : 0.f;
    }
    __syncthreads();
    // stage0: conv1+relu -> E0/O0 (8 x 148), outputs rel j in [0, 282)
    {
        const int ch = tid & 7;
        const int pj = tid >> 3;   // 0..31, parity fixed
        float wa = c1w[ch * 3], wb = c1w[ch * 3 + 1], wc = c1w[ch * 3 + 2], bc = c1b[ch];
        float* tgt = lds + ((pj & 1) ? O0_OFF : E0_OFF) + ch * 148;
        const int kb = pj >> 1;
        for (int k = 0; k < 9; ++k) {
            int j = pj + 32 * k;
            if (j >= 282) break;
            int l = a0 + j;
            float v = 0.f;
            if (l >= 0 && l < L0)
                v = fmaxf(fmaf(wa, xb[j], fmaf(wb, xb[j + 1], fmaf(wc, xb[j + 2], bc))), 0.f);
            tgt[kb + 16 * k] = v;
        }
    }
    const int ea = tidx[b * 2], eb2i = tidx[b * 2 + 1];
    const float ga = tg[b * 2], gb2 = tg[b * 2 + 1];
    // per-stage thread coords
    const int cg1 = tid & 7,  pg1 = tid >> 3;   // stage1: 8 ch-pairs x 32 pos-groups
    const int cg2 = tid & 15, pg2 = tid >> 4;   // stage2: 16 ch-pairs x 16 pos-groups
    const int cg3 = tid >> 3, pg3 = tid & 7;    // stage3: 32 ch-pairs x 8 pos-groups
    const int co1 = 2 * cg1, co2 = 2 * cg2, co3 = 2 * cg3;
    const int j3 = 4 * pg3;
    float oa[2][4];
#pragma unroll
    for (int c = 0; c < 2; c++)
#pragma unroll
        for (int p = 0; p < 4; p++) oa[c][p] = 0.f;
#pragma unroll 1
    for (int slot = 0; slot < 2; ++slot) {
        const int e = slot ? eb2i : ea;
        const float g = slot ? gb2 : ga;
        __syncthreads();   // E0/O0 ready (slot0) / prev slot E2 readers done
        // stage1: CI=8 CO=16, JOUT=138
        {
            const float* wp = w1p + e * 512;
            float2 bb = *reinterpret_cast<const float2*>(b1p + e * 16 + co1);
            stage2ch<8, 16, 148, 76, 1024, 138, false>(wp, bb.x, bb.y,
                lds + E0_OFF, lds + O0_OFF, lds + E1_OFF, lds + O1_OFF, a1, co1, 4 * pg1);
            if (pg1 < 3)
                stage2ch<8, 16, 148, 76, 1024, 138, true>(wp, bb.x, bb.y,
                    lds + E0_OFF, lds + O0_OFF, lds + E1_OFF, lds + O1_OFF, a1, co1, 128 + 4 * pg1);
        }
        __syncthreads();
        // stage2: CI=16 CO=32, JOUT=66
        {
            const float* wp = w2p + e * 2048;
            float2 bb = *reinterpret_cast<const float2*>(b2p + e * 32 + co2);
            stage2ch<16, 32, 76, 36, 512, 66, false>(wp, bb.x, bb.y,
                lds + E1_OFF, lds + O1_OFF, lds + E2_OFF, lds + O2_OFF, a2, co2, 4 * pg2);
            if (pg2 == 0)
                stage2ch<16, 32, 76, 36, 512, 66, true>(wp, bb.x, bb.y,
                    lds + E1_OFF, lds + O1_OFF, lds + E2_OFF, lds + O2_OFF, a2, co2, 64);
        }
        __syncthreads();
        // stage3: CI=32 CO=64, JOUT=32 exact
        {
            const float* wp = w3p + e * 8192;
            float2 bb = *reinterpret_cast<const float2*>(b3p + e * 64 + co3);
            stage3_2ch(wp, bb.x, bb.y, lds + E2_OFF, lds + O2_OFF, g, oa, co3, j3);
        }
    }
    // comb[b][co][a3 + j], coalesced float4 over pg3
    float* cb = comb + (size_t)b * 16384 + (size_t)co3 * 256 + a3 + j3;
    *reinterpret_cast<float4*>(cb)       = make_float4(oa[0][0], oa[0][1], oa[0][2], oa[0][3]);
    *reinterpret_cast<float4*>(cb + 256) = make_float4(oa[1][0], oa[1][1], oa[1][2], oa[1][3]);
}

// ---------------- fc1 split-K GEMM: P[kc][b][64] = partial(flat @ fc1_w.T) ----------------
__global__ __launch_bounds__(256) void fc1_kernel(const float* __restrict__ comb,
    const float* __restrict__ w, float* __restrict__ P)
{
    __shared__ __align__(16) float at[64 * 65];
    __shared__ __align__(16) float wt[64 * 65];
    int bc = blockIdx.x;   // 0..15 row chunk
    int kc = blockIdx.y;   // 0..7  k chunk
    int tid = threadIdx.x;
    int tx = tid & 15, ty = tid >> 4;
    float acc[4][4];
#pragma unroll
    for (int i = 0; i < 4; i++)
#pragma unroll
        for (int j = 0; j < 4; j++) acc[i][j] = 0.f;
    int b0 = bc * 64;
    for (int kt = 0; kt < 32; ++kt) {
        int k0 = kc * 2048 + kt * 64;
        __syncthreads();
        for (int i = tid; i < 4096; i += 256) {
            int r = i >> 6, kk = i & 63;
            at[r * 65 + kk] = comb[(size_t)(b0 + r) * 16384 + k0 + kk];
            wt[r * 65 + kk] = w[(size_t)r * 16384 + k0 + kk];
        }
        __syncthreads();
#pragma unroll 8
        for (int kk = 0; kk < 64; kk++) {
            float av[4], wv[4];
#pragma unroll
            for (int i = 0; i < 4; i++) av[i] = at[(ty * 4 + i) * 65 + kk];
#pragma unroll
            for (int j = 0; j < 4; j++) wv[j] = wt[(tx * 4 + j) * 65 + kk];
#pragma unroll
            for (int i = 0; i < 4; i++)
#pragma unroll
                for (int j = 0; j < 4; j++) acc[i][j] = fmaf(av[i], wv[j], acc[i][j]);
        }
    }
    float* Pp = P + (size_t)kc * 65536;
#pragma unroll
    for (int i = 0; i < 4; i++)
#pragma unroll
        for (int j = 0; j < 4; j++)
            Pp[(size_t)(b0 + ty * 4 + i) * 64 + tx * 4 + j] = acc[i][j];
}

// ---------------- reduce partials + bias + relu + fc2 ----------------
__global__ __launch_bounds__(256) void fc2_kernel(const float* __restrict__ P,
    const float* __restrict__ f1b, const float* __restrict__ w2, const float* __restrict__ b2,
    float* __restrict__ out)
{
    int b = blockIdx.x * 256 + threadIdx.x;  // 0..1023
    float z[64];
#pragma unroll
    for (int n = 0; n < 64; n++) z[n] = 0.f;
    for (int kc = 0; kc < 8; kc++) {
        const float* Pp = P + (size_t)kc * 65536 + (size_t)b * 64;
#pragma unroll
        for (int n = 0; n < 64; n++) z[n] += Pp[n];
    }
    float o[5] = {0.f, 0.f, 0.f, 0.f, 0.f};
#pragma unroll
    for (int n = 0; n < 64; n++) {
        float zz = fmaxf(z[n] + f1b[n], 0.f);
#pragma unroll
        for (int c = 0; c < 5; c++) o[c] = fmaf(zz, w2[c * 64 + n], o[c]);
    }
#pragma unroll
    for (int c = 0; c < 5; c++) out[b * 5 + c] = o[c] + b2[c];
}

extern "C" void kernel_launch(void* const* d_in, const int* in_sizes, int n_in,
                              void* d_out, int out_size, void* d_ws, size_t ws_size,
                              hipStream_t stream)
{
    const float* x   = (const float*)d_in[0];
    const float* c1w = (const float*)d_in[1];
    const float* c1b = (const float*)d_in[2];
    const float* ew1 = (const float*)d_in[3];
    const float* eb1 = (const float*)d_in[4];
    const float* g1  = (const float*)d_in[5];
    const float* bb1 = (const float*)d_in[6];
    const float* m1  = (const float*)d_in[7];
    const float* v1  = (const float*)d_in[8];
    const float* ew2 = (const float*)d_in[9];
    const float* eb2 = (const float*)d_in[10];
    const float* g2  = (const float*)d_in[11];
    const float* bb2 = (const float*)d_in[12];
    const float* m2  = (const float*)d_in[13];
    const float* v2  = (const float*)d_in[14];
    const float* ew3 = (const float*)d_in[15];
    const float* eb3 = (const float*)d_in[16];
    const float* g3  = (const float*)d_in[17];
    const float* bb3 = (const float*)d_in[18];
    const float* m3  = (const float*)d_in[19];
    const float* v3  = (const float*)d_in[20];
    const float* rw  = (const float*)d_in[21];
    const float* rb  = (const float*)d_in[22];
    const float* f1w = (const float*)d_in[23];
    const float* f1b = (const float*)d_in[24];
    const float* f2w = (const float*)d_in[25];
    const float* f2b = (const float*)d_in[26];

    float* ws     = (float*)d_ws;
    float* pooled = ws + OFF_POOLED;
    int*   tidx   = (int*)(ws + OFF_TOPKI);
    float* tg     = ws + OFF_TOPKG;
    float* b1p    = ws + OFF_B1;
    float* b2p    = ws + OFF_B2;
    float* b3p    = ws + OFF_B3;
    float* w1p    = ws + OFF_W1P;
    float* w2p    = ws + OFF_W2P;
    float* w3p    = ws + OFF_W3P;
    float* comb   = ws + OFF_COMB;
    float* P      = ws + OFF_P;
    float* out    = (float*)d_out;

    hipLaunchKernelGGL(pool_kernel, dim3(1024), dim3(256), 0, stream, x, c1w, c1b, pooled);
    hipLaunchKernelGGL(repack_kernel, dim3(170), dim3(256), 0, stream,
                       ew1, eb1, g1, bb1, m1, v1, ew2, eb2, g2, bb2, m2, v2,
                       ew3, eb3, g3, bb3, m3, v3, w1p, w2p, w3p, b1p, b2p, b3p);
    hipLaunchKernelGGL(router_kernel, dim3(1), dim3(1024), 0, stream, pooled, rw, rb, tidx, tg, out + 5120);
    hipLaunchKernelGGL(expert_kernel, dim3(8192), dim3(256), 0, stream,
                       x, c1w, c1b, w1p, w2p, w3p, b1p, b2p, b3p, tidx, tg, comb);
    hipLaunchKernelGGL(fc1_kernel, dim3(16, 8), dim3(256), 0, stream, comb, f1w, P);
    hipLaunchKernelGGL(fc2_kernel, dim3(4), dim3(256), 0, stream, P, f1b, f2w, f2b, out);
}

// Round 5
// 409.773 us; speedup vs baseline: 3.0544x; 1.2230x over previous
//
#include <hip/hip_runtime.h>

// ---------------- workspace layout (float offsets) ----------------
constexpr int L0 = 2048;
constexpr size_t OFF_POOLED = 0;                  // 1024*8
constexpr size_t OFF_TOPKI  = 8192;               // 2048 ints
constexpr size_t OFF_TOPKG  = 10240;              // 2048 floats
constexpr size_t OFF_B1     = 12288;              // 64
constexpr size_t OFF_B2     = 12352;              // 128
constexpr size_t OFF_B3     = 12480;              // 256
constexpr size_t OFF_W1Q    = 12800;              // 2048  [e][co16][ci8][4]
constexpr size_t OFF_W2Q    = 14848;              // 8192  [e][co32][ci16][4]
constexpr size_t OFF_W3Q    = 23040;              // 32768 [e][co64][ci32][4]
constexpr size_t OFF_COMB   = 57344;              // 1024*16384
constexpr size_t OFF_P      = 57344 + 16777216;   // 16*1024*64

// ---------------- pooling kernel: pooled[b,c] = mean_l relu(conv1(x)) ----------------
__global__ __launch_bounds__(256) void pool_kernel(const float* __restrict__ x,
    const float* __restrict__ c1w, const float* __restrict__ c1b, float* __restrict__ pooled)
{
    __shared__ float xbuf[2050];
    __shared__ float part[4][8];
    int b = blockIdx.x, tid = threadIdx.x;
    const float* xr = x + (size_t)b * L0;
    for (int i = tid; i < 2050; i += 256) xbuf[i] = (i >= 1 && i <= L0) ? xr[i - 1] : 0.f;
    __syncthreads();
    float w[24], bb[8];
#pragma unroll
    for (int i = 0; i < 24; i++) w[i] = c1w[i];
#pragma unroll
    for (int c = 0; c < 8; c++) bb[c] = c1b[c];
    float acc[8];
#pragma unroll
    for (int c = 0; c < 8; c++) acc[c] = 0.f;
    for (int l = tid; l < L0; l += 256) {
        float xm = xbuf[l], x0 = xbuf[l + 1], xp = xbuf[l + 2];
#pragma unroll
        for (int c = 0; c < 8; c++)
            acc[c] += fmaxf(fmaf(w[3 * c], xm, fmaf(w[3 * c + 1], x0, fmaf(w[3 * c + 2], xp, bb[c]))), 0.f);
    }
#pragma unroll
    for (int c = 0; c < 8; c++) {
#pragma unroll
        for (int off = 32; off > 0; off >>= 1)
            acc[c] += __shfl_down(acc[c], off, 64);
    }
    int wv = tid >> 6, ln = tid & 63;
    if (ln == 0) {
#pragma unroll
        for (int c = 0; c < 8; c++) part[wv][c] = acc[c];
    }
    __syncthreads();
    if (tid < 8) {
        float s = part[0][tid] + part[1][tid] + part[2][tid] + part[3][tid];
        pooled[b * 8 + tid] = s * (1.f / L0);
    }
}

// ---------------- weight repack + BN fold: wq[e][co][ci][4] ----------------
__global__ __launch_bounds__(256) void repack_kernel(
    const float* __restrict__ ew1, const float* __restrict__ eb1, const float* __restrict__ g1,
    const float* __restrict__ bb1, const float* __restrict__ m1, const float* __restrict__ v1,
    const float* __restrict__ ew2, const float* __restrict__ eb2, const float* __restrict__ g2,
    const float* __restrict__ bb2, const float* __restrict__ m2, const float* __restrict__ v2,
    const float* __restrict__ ew3, const float* __restrict__ eb3, const float* __restrict__ g3,
    const float* __restrict__ bb3, const float* __restrict__ m3, const float* __restrict__ v3,
    float* __restrict__ w1q, float* __restrict__ w2q, float* __restrict__ w3q,
    float* __restrict__ b1p, float* __restrict__ b2p, float* __restrict__ b3p)
{
    int i = blockIdx.x * 256 + threadIdx.x;
    if (i < 2048) {
        int k = i & 3, ci = (i >> 2) & 7, co = (i >> 5) & 15, e = i >> 9;
        int ec = e * 16 + co;
        float A = g1[ec] * rsqrtf(v1[ec] + 1e-5f);
        w1q[i] = (k < 3) ? ew1[(ec * 8 + ci) * 3 + k] * A : 0.f;
    } else if (i < 10240) {
        int ii = i - 2048;
        int k = ii & 3, ci = (ii >> 2) & 15, co = (ii >> 6) & 31, e = ii >> 11;
        int ec = e * 32 + co;
        float A = g2[ec] * rsqrtf(v2[ec] + 1e-5f);
        w2q[ii] = (k < 3) ? ew2[(ec * 16 + ci) * 3 + k] * A : 0.f;
    } else if (i < 43008) {
        int ii = i - 10240;
        int k = ii & 3, ci = (ii >> 2) & 31, co = (ii >> 7) & 63, e = ii >> 13;
        int ec = e * 64 + co;
        float A = g3[ec] * rsqrtf(v3[ec] + 1e-5f);
        w3q[ii] = (k < 3) ? ew3[(ec * 32 + ci) * 3 + k] * A : 0.f;
    } else if (i < 43456) {
        int j = i - 43008;
        if (j < 64)       { float A = g1[j] * rsqrtf(v1[j] + 1e-5f); b1p[j] = fmaf(eb1[j] - m1[j], A, bb1[j]); }
        else if (j < 192) { int q = j - 64;  float A = g2[q] * rsqrtf(v2[q] + 1e-5f); b2p[q] = fmaf(eb2[q] - m2[q], A, bb2[q]); }
        else              { int q = j - 192; float A = g3[q] * rsqrtf(v3[q] + 1e-5f); b3p[q] = fmaf(eb3[q] - m3[q], A, bb3[q]); }
    }
}

// ---------------- router: softmax, top-2, gates, aux loss ----------------
__global__ __launch_bounds__(1024) void router_kernel(const float* __restrict__ pooled,
    const float* __restrict__ rw, const float* __restrict__ rb,
    int* __restrict__ tidx, float* __restrict__ tg, float* __restrict__ aux)
{
    __shared__ float pr[4][1024];
    int b = threadIdx.x;
    float p[8];
#pragma unroll
    for (int c = 0; c < 8; c++) p[c] = pooled[b * 8 + c];
    float lg[4];
#pragma unroll
    for (int e = 0; e < 4; e++) {
        float a = rb[e];
#pragma unroll
        for (int c = 0; c < 8; c++) a = fmaf(p[c], rw[e * 8 + c], a);
        lg[e] = a;
    }
    float m = fmaxf(fmaxf(lg[0], lg[1]), fmaxf(lg[2], lg[3]));
    float pe[4]; float s = 0.f;
#pragma unroll
    for (int e = 0; e < 4; e++) { pe[e] = expf(lg[e] - m); s += pe[e]; }
    float inv = 1.f / s;
#pragma unroll
    for (int e = 0; e < 4; e++) pe[e] *= inv;
    int e0 = 0;
#pragma unroll
    for (int e = 1; e < 4; e++) if (pe[e] > pe[e0]) e0 = e;
    int e1 = -1;
#pragma unroll
    for (int e = 0; e < 4; e++) if (e != e0 && (e1 < 0 || pe[e] > pe[e1])) e1 = e;
    float s2 = pe[e0] + pe[e1];
    tidx[b * 2] = e0; tidx[b * 2 + 1] = e1;
    tg[b * 2] = pe[e0] / s2; tg[b * 2 + 1] = pe[e1] / s2;
#pragma unroll
    for (int e = 0; e < 4; e++) pr[e][b] = pe[e];
    __syncthreads();
    for (int off = 512; off > 0; off >>= 1) {
        if (b < off) {
#pragma unroll
            for (int e = 0; e < 4; e++) pr[e][b] += pr[e][b + off];
        }
        __syncthreads();
    }
    if (b == 0) {
        float mp[4]; float mm = 0.f;
#pragma unroll
        for (int e = 0; e < 4; e++) { mp[e] = pr[e][0] * (1.f / 1024.f); mm += mp[e]; }
        mm *= 0.25f;
        float var = 0.f;
#pragma unroll
        for (int e = 0; e < 4; e++) { float d = mp[e] - mm; var += d * d; }
        var *= (1.f / 3.f);
        float cv = sqrtf(var) / (mm + 1e-10f);
        aux[0] = cv * cv;
    }
}

// ---------------- expert chain, T=32 final positions per block ----------------
constexpr int XB_OFF = 0;      // 284 (pad 288)
constexpr int E0_OFF = 288;    // 8 x 148
constexpr int O0_OFF = 1472;   // 8 x 148
constexpr int E1_OFF = 2656;   // 16 x 76
constexpr int O1_OFF = 3872;   // 16 x 76
constexpr int E2_OFF = 5088;   // 32 x 36
constexpr int O2_OFF = 6240;   // 32 x 36
constexpr int LDS_FLOATS = 7392;   // 29568 B -> 5 blocks/CU

// 1 output channel x 8 positions; weights per-channel-contiguous (immediate offsets)
template<int CI, int SIN>
__device__ __forceinline__ void conv1ch8(
    const float* __restrict__ wq,   // [CI][4] for this (e,co)
    const float bias,
    const float* __restrict__ Ein, const float* __restrict__ Oin,
    const int j0, float vE[8], float vO[8])
{
#pragma unroll
    for (int p = 0; p < 8; ++p) { vE[p] = bias; vO[p] = bias; }
#pragma unroll
    for (int ci = 0; ci < CI; ++ci) {
        const float4 w = *reinterpret_cast<const float4*>(wq + ci * 4);
        const float* ep = Ein + ci * SIN + j0;
        const float4 ea = *reinterpret_cast<const float4*>(ep);
        const float4 eb = *reinterpret_cast<const float4*>(ep + 4);
        const float e8 = ep[8];
        const float* op = Oin + ci * SIN + j0;
        const float4 oa = *reinterpret_cast<const float4*>(op);
        const float4 ob = *reinterpret_cast<const float4*>(op + 4);
        const float o8 = op[8];
        const float E[9] = {ea.x, ea.y, ea.z, ea.w, eb.x, eb.y, eb.z, eb.w, e8};
        const float O[9] = {oa.x, oa.y, oa.z, oa.w, ob.x, ob.y, ob.z, ob.w, o8};
#pragma unroll
        for (int p = 0; p < 8; ++p) {
            vE[p] = fmaf(w.x, E[p], fmaf(w.y, O[p], fmaf(w.z, E[p + 1], vE[p])));
            vO[p] = fmaf(w.x, O[p], fmaf(w.y, E[p + 1], fmaf(w.z, O[p + 1], vO[p])));
        }
    }
}

// pool+relu+guard, store to E/O split output
template<int SOUT, int LOUT, bool GUARDJ>
__device__ __forceinline__ void pool_store(
    const float vE[8], const float vO[8],
    float* __restrict__ Eout, float* __restrict__ Oout,
    const int co, const int j0, const int a_out, const int jmax)
{
    float v[8];
#pragma unroll
    for (int p = 0; p < 8; ++p) {
        int l = a_out + j0 + p;
        bool ok = (l >= 0) && (l < LOUT);
        if (GUARDJ) ok = ok && (j0 + p < jmax);
        v[p] = ok ? fmaxf(fmaxf(vE[p], vO[p]), 0.f) : 0.f;
    }
    *reinterpret_cast<float4*>(Eout + co * SOUT + (j0 >> 1)) = make_float4(v[0], v[2], v[4], v[6]);
    *reinterpret_cast<float4*>(Oout + co * SOUT + (j0 >> 1)) = make_float4(v[1], v[3], v[5], v[7]);
}

__global__ __launch_bounds__(256, 5) void expert_kernel(
    const float* __restrict__ x, const float* __restrict__ c1w, const float* __restrict__ c1b,
    const float* __restrict__ w1q, const float* __restrict__ w2q, const float* __restrict__ w3q,
    const float* __restrict__ b1p, const float* __restrict__ b2p, const float* __restrict__ b3p,
    const int* __restrict__ tidx, const float* __restrict__ tg,
    float* __restrict__ comb)
{
    __shared__ __align__(16) float lds[LDS_FLOATS];
    const int tid = threadIdx.x;
    const int bt = blockIdx.x;
    const int b = bt >> 3, t = bt & 7;
    const int a3 = t * 32, a2 = 2 * a3 - 1, a1 = 4 * a3 - 3, a0 = 8 * a3 - 7;
    const float* xr = x + (size_t)b * L0;
    float* xb = lds + XB_OFF;
    for (int m = tid; m < 284; m += 256) {
        int gpos = a0 - 1 + m;
        xb[m] = (gpos >= 0 && gpos < L0) ? xr[gpos] : 0.f;
    }
    __syncthreads();
    // stage0: conv1+relu -> E0/O0 (8 x 148), rel j in [0, 282)
    {
        const int ch = tid & 7;
        const int pj = tid >> 3;   // 0..31, parity fixed
        float wa = c1w[ch * 3], wb = c1w[ch * 3 + 1], wc = c1w[ch * 3 + 2], bc = c1b[ch];
        float* tgt = lds + ((pj & 1) ? O0_OFF : E0_OFF) + ch * 148;
        const int kb = pj >> 1;
        for (int k = 0; k < 9; ++k) {
            int j = pj + 32 * k;
            if (j >= 282) break;
            int l = a0 + j;
            float v = 0.f;
            if (l >= 0 && l < L0)
                v = fmaxf(fmaf(wa, xb[j], fmaf(wb, xb[j + 1], fmaf(wc, xb[j + 2], bc))), 0.f);
            tgt[kb + 16 * k] = v;
        }
    }
    const int ea = tidx[b * 2], eb2i = tidx[b * 2 + 1];
    const float ga = tg[b * 2], gb2 = tg[b * 2 + 1];
    // thread maps: tails confined to wave 0
    const int co1 = tid & 15, pg1 = tid >> 4;   // stage1: 16 ch x 16 pos-groups(8)
    const int co2 = tid & 31, pg2 = tid >> 5;   // stage2: 32 ch x 8 pos-groups(8)
    const int co3 = tid >> 2, pg3 = tid & 3;    // stage3: 64 ch x 4 pos-groups(8)
    const int j3 = 8 * pg3;
    float oacc[8];
#pragma unroll
    for (int p = 0; p < 8; p++) oacc[p] = 0.f;
    float vE[8], vO[8];
#pragma unroll 1
    for (int slot = 0; slot < 2; ++slot) {
        const int e = slot ? eb2i : ea;
        const float g = slot ? gb2 : ga;
        __syncthreads();   // E0/O0 ready (slot0) / prev-slot E1 readers done
        // stage1: CI=8 CO=16, JOUT=138
        {
            const float* wq = w1q + (size_t)(e * 16 + co1) * 32;
            const float bias = b1p[e * 16 + co1];
            conv1ch8<8, 148>(wq, bias, lds + E0_OFF, lds + O0_OFF, 8 * pg1, vE, vO);
            pool_store<76, 1024, false>(vE, vO, lds + E1_OFF, lds + O1_OFF, co1, 8 * pg1, a1, 138);
            if (pg1 < 2) {
                int j0 = 128 + 8 * pg1;
                conv1ch8<8, 148>(wq, bias, lds + E0_OFF, lds + O0_OFF, j0, vE, vO);
                pool_store<76, 1024, true>(vE, vO, lds + E1_OFF, lds + O1_OFF, co1, j0, a1, 138);
            }
        }
        __syncthreads();
        // stage2: CI=16 CO=32, JOUT=66
        {
            const float* wq = w2q + (size_t)(e * 32 + co2) * 64;
            const float bias = b2p[e * 32 + co2];
            conv1ch8<16, 76>(wq, bias, lds + E1_OFF, lds + O1_OFF, 8 * pg2, vE, vO);
            pool_store<36, 512, false>(vE, vO, lds + E2_OFF, lds + O2_OFF, co2, 8 * pg2, a2, 66);
            if (pg2 == 0) {
                conv1ch8<16, 76>(wq, bias, lds + E1_OFF, lds + O1_OFF, 64, vE, vO);
                pool_store<36, 512, true>(vE, vO, lds + E2_OFF, lds + O2_OFF, co2, 64, a2, 66);
            }
        }
        __syncthreads();
        // stage3: CI=32 CO=64, JOUT=32 exact; gated accumulate in regs
        {
            const float* wq = w3q + (size_t)(e * 64 + co3) * 128;
            const float bias = b3p[e * 64 + co3];
            conv1ch8<32, 36>(wq, bias, lds + E2_OFF, lds + O2_OFF, j3, vE, vO);
#pragma unroll
            for (int p = 0; p < 8; ++p)
                oacc[p] = fmaf(g, fmaxf(fmaxf(vE[p], vO[p]), 0.f), oacc[p]);
        }
    }
    // comb[b][co][a3 + j3 .. +8]
    float* cb = comb + (size_t)b * 16384 + (size_t)co3 * 256 + a3 + j3;
    *reinterpret_cast<float4*>(cb)     = make_float4(oacc[0], oacc[1], oacc[2], oacc[3]);
    *reinterpret_cast<float4*>(cb + 4) = make_float4(oacc[4], oacc[5], oacc[6], oacc[7]);
}

// ---------------- fc1 split-K GEMM: P[kc][b][64] = partial(flat @ fc1_w.T) ----------------
__global__ __launch_bounds__(256) void fc1_kernel(const float* __restrict__ comb,
    const float* __restrict__ w, float* __restrict__ P)
{
    __shared__ __align__(16) float at[64 * 65];
    __shared__ __align__(16) float wt[64 * 65];
    int bc = blockIdx.x;   // 0..15 row chunk
    int kc = blockIdx.y;   // 0..15 k chunk
    int tid = threadIdx.x;
    int tx = tid & 15, ty = tid >> 4;
    float acc[4][4];
#pragma unroll
    for (int i = 0; i < 4; i++)
#pragma unroll
        for (int j = 0; j < 4; j++) acc[i][j] = 0.f;
    int b0 = bc * 64;
    for (int kt = 0; kt < 16; ++kt) {
        int k0 = kc * 1024 + kt * 64;
        __syncthreads();
        for (int i = tid; i < 4096; i += 256) {
            int r = i >> 6, kk = i & 63;
            at[r * 65 + kk] = comb[(size_t)(b0 + r) * 16384 + k0 + kk];
            wt[r * 65 + kk] = w[(size_t)r * 16384 + k0 + kk];
        }
        __syncthreads();
#pragma unroll 8
        for (int kk = 0; kk < 64; kk++) {
            float av[4], wv[4];
#pragma unroll
            for (int i = 0; i < 4; i++) av[i] = at[(ty * 4 + i) * 65 + kk];
#pragma unroll
            for (int j = 0; j < 4; j++) wv[j] = wt[(tx * 4 + j) * 65 + kk];
#pragma unroll
            for (int i = 0; i < 4; i++)
#pragma unroll
                for (int j = 0; j < 4; j++) acc[i][j] = fmaf(av[i], wv[j], acc[i][j]);
        }
    }
    float* Pp = P + (size_t)kc * 65536;
#pragma unroll
    for (int i = 0; i < 4; i++)
#pragma unroll
        for (int j = 0; j < 4; j++)
            Pp[(size_t)(b0 + ty * 4 + i) * 64 + tx * 4 + j] = acc[i][j];
}

// ---------------- reduce partials + bias + relu + fc2 ----------------
__global__ __launch_bounds__(64) void fc2_kernel(const float* __restrict__ P,
    const float* __restrict__ f1b, const float* __restrict__ w2, const float* __restrict__ b2,
    float* __restrict__ out)
{
    int b = blockIdx.x * 64 + threadIdx.x;  // 0..1023
    float z[64];
#pragma unroll
    for (int n = 0; n < 64; n++) z[n] = 0.f;
    for (int kc = 0; kc < 16; kc++) {
        const float* Pp = P + (size_t)kc * 65536 + (size_t)b * 64;
#pragma unroll
        for (int n = 0; n < 64; n++) z[n] += Pp[n];
    }
    float o[5] = {0.f, 0.f, 0.f, 0.f, 0.f};
#pragma unroll
    for (int n = 0; n < 64; n++) {
        float zz = fmaxf(z[n] + f1b[n], 0.f);
#pragma unroll
        for (int c = 0; c < 5; c++) o[c] = fmaf(zz, w2[c * 64 + n], o[c]);
    }
#pragma unroll
    for (int c = 0; c < 5; c++) out[b * 5 + c] = o[c] + b2[c];
}

extern "C" void kernel_launch(void* const* d_in, const int* in_sizes, int n_in,
                              void* d_out, int out_size, void* d_ws, size_t ws_size,
                              hipStream_t stream)
{
    const float* x   = (const float*)d_in[0];
    const float* c1w = (const float*)d_in[1];
    const float* c1b = (const float*)d_in[2];
    const float* ew1 = (const float*)d_in[3];
    const float* eb1 = (const float*)d_in[4];
    const float* g1  = (const float*)d_in[5];
    const float* bb1 = (const float*)d_in[6];
    const float* m1  = (const float*)d_in[7];
    const float* v1  = (const float*)d_in[8];
    const float* ew2 = (const float*)d_in[9];
    const float* eb2 = (const float*)d_in[10];
    const float* g2  = (const float*)d_in[11];
    const float* bb2 = (const float*)d_in[12];
    const float* m2  = (const float*)d_in[13];
    const float* v2  = (const float*)d_in[14];
    const float* ew3 = (const float*)d_in[15];
    const float* eb3 = (const float*)d_in[16];
    const float* g3  = (const float*)d_in[17];
    const float* bb3 = (const float*)d_in[18];
    const float* m3  = (const float*)d_in[19];
    const float* v3  = (const float*)d_in[20];
    const float* rw  = (const float*)d_in[21];
    const float* rb  = (const float*)d_in[22];
    const float* f1w = (const float*)d_in[23];
    const float* f1b = (const float*)d_in[24];
    const float* f2w = (const float*)d_in[25];
    const float* f2b = (const float*)d_in[26];

    float* ws     = (float*)d_ws;
    float* pooled = ws + OFF_POOLED;
    int*   tidx   = (int*)(ws + OFF_TOPKI);
    float* tg     = ws + OFF_TOPKG;
    float* b1p    = ws + OFF_B1;
    float* b2p    = ws + OFF_B2;
    float* b3p    = ws + OFF_B3;
    float* w1q    = ws + OFF_W1Q;
    float* w2q    = ws + OFF_W2Q;
    float* w3q    = ws + OFF_W3Q;
    float* comb   = ws + OFF_COMB;
    float* P      = ws + OFF_P;
    float* out    = (float*)d_out;

    hipLaunchKernelGGL(pool_kernel, dim3(1024), dim3(256), 0, stream, x, c1w, c1b, pooled);
    hipLaunchKernelGGL(repack_kernel, dim3(170), dim3(256), 0, stream,
                       ew1, eb1, g1, bb1, m1, v1, ew2, eb2, g2, bb2, m2, v2,
                       ew3, eb3, g3, bb3, m3, v3, w1q, w2q, w3q, b1p, b2p, b3p);
    hipLaunchKernelGGL(router_kernel, dim3(1), dim3(1024), 0, stream, pooled, rw, rb, tidx, tg, out + 5120);
    hipLaunchKernelGGL(expert_kernel, dim3(8192), dim3(256), 0, stream,
                       x, c1w, c1b, w1q, w2q, w3q, b1p, b2p, b3p, tidx, tg, comb);
    hipLaunchKernelGGL(fc1_kernel, dim3(16, 16), dim3(256), 0, stream, comb, f1w, P);
    hipLaunchKernelGGL(fc2_kernel, dim3(16), dim3(64), 0, stream, P, f1b, f2w, f2b, out);
}